// Round 2
// baseline (829.560 us; speedup 1.0000x reference)
//
#include <hip/hip_runtime.h>
#include <hip/hip_bf16.h>

#define N_NODES 50000
#define N_EDGES 600000
#define DIM_H   128

__device__ __forceinline__ float b2f(__hip_bfloat16 x) { return __bfloat162float(x); }

// ---------------------------------------------------------------------------
// K1: column sums of nodes (for global mean feature)
// ---------------------------------------------------------------------------
__global__ __launch_bounds__(128) void colsum_k(const float* __restrict__ nodes,
                                                float* __restrict__ colsum) {
    int c = threadIdx.x;               // 0..127
    float s = 0.f;
    for (int r = blockIdx.x; r < N_NODES; r += gridDim.x)
        s += nodes[(size_t)r * DIM_H + c];
    unsafeAtomicAdd(&colsum[c], s);
}

// ---------------------------------------------------------------------------
// K2: edge scatter  agg[dst] += nodes[src], deg[dst] += 1
// 2 edges per 256-thread block; 128 lanes per edge (one per feature)
// ---------------------------------------------------------------------------
__global__ __launch_bounds__(256) void scatter_k(const float* __restrict__ nodes,
                                                 const int* __restrict__ esrc,
                                                 const int* __restrict__ edst,
                                                 float* __restrict__ agg,
                                                 float* __restrict__ deg) {
    int e = blockIdx.x * 2 + (threadIdx.x >> 7);
    int j = threadIdx.x & 127;
    if (e >= N_EDGES) return;
    int src = esrc[e];
    int dst = edst[e];
    float v = nodes[(size_t)src * DIM_H + j];
    unsafeAtomicAdd(&agg[(size_t)dst * DIM_H + j], v);
    if (j == 0) unsafeAtomicAdd(&deg[dst], 1.0f);
}

// ---------------------------------------------------------------------------
// Tiled f32 GEMM: C[M x Nout] = A[M x 128] * W[Nout x 128]^T  (dot over K=128)
// 64x64 tile per 256-thread block, full K staged once in LDS (transposed,
// pad 68 floats/row -> 16B-aligned rows, conflict-free float4 compute reads).
// MODE 0: A=agg,   epilogue msgin = C + deg*b_msg + mean   (f32 out)
// MODE 1: A=msgin, epilogue gi = C + b_ih                  (bf16 out)
// MODE 2: A=nodes, epilogue gh = C + b_hh                  (bf16 out)
// ---------------------------------------------------------------------------
template <int MODE>
__global__ __launch_bounds__(256) void gemm_k(const float* __restrict__ A,
                                              const float* __restrict__ W,
                                              const float* __restrict__ bias,
                                              const float* __restrict__ deg,
                                              const float* __restrict__ colsum,
                                              float* __restrict__ out_f,
                                              __hip_bfloat16* __restrict__ out_b,
                                              int M, int Nout) {
    __shared__ float As[128][68];   // As[k][m]
    __shared__ float Ws[128][68];   // Ws[k][n]
    const int tid = threadIdx.x;
    const int m0 = blockIdx.x * 64;
    const int n0 = blockIdx.y * 64;

    // stage A (coalesced global reads; LDS transpose writes, once/block)
    for (int i = tid; i < 64 * 128; i += 256) {
        int m = i >> 7, k = i & 127;
        int gm = m0 + m;
        As[k][m] = (gm < M) ? A[(size_t)gm * 128 + k] : 0.f;
    }
    // stage W
    for (int i = tid; i < 64 * 128; i += 256) {
        int n = i >> 7, k = i & 127;
        Ws[k][n] = W[(size_t)(n0 + n) * 128 + k];
    }
    __syncthreads();

    const int tx = tid & 15;   // n-dim (4 cols)
    const int ty = tid >> 4;   // m-dim (4 rows)
    float acc[4][4] = {};
#pragma unroll 4
    for (int k = 0; k < 128; ++k) {
        float4 a = *(const float4*)&As[k][ty * 4];
        float4 b = *(const float4*)&Ws[k][tx * 4];
        float av[4] = {a.x, a.y, a.z, a.w};
        float bv[4] = {b.x, b.y, b.z, b.w};
#pragma unroll
        for (int i = 0; i < 4; ++i)
#pragma unroll
            for (int j = 0; j < 4; ++j)
                acc[i][j] = fmaf(av[i], bv[j], acc[i][j]);
    }

#pragma unroll
    for (int i = 0; i < 4; ++i) {
        int m = m0 + ty * 4 + i;
        if (m < M) {
#pragma unroll
            for (int j = 0; j < 4; ++j) {
                int n = n0 + tx * 4 + j;
                float c = acc[i][j];
                if (MODE == 0) {
                    out_f[(size_t)m * 128 + n] =
                        c + deg[m] * bias[n] + colsum[n] * (1.0f / N_NODES);
                } else {
                    out_b[(size_t)m * Nout + n] = __float2bfloat16(c + bias[n]);
                }
            }
        }
    }
}

// ---------------------------------------------------------------------------
// K5: GRU gates + LayerNorm + residual. One wave (64 lanes) per node,
// 2 columns per lane; shuffle reductions for mean/var.
// ---------------------------------------------------------------------------
__global__ __launch_bounds__(256) void fuse_k(const float* __restrict__ nodes,
                                              const __hip_bfloat16* __restrict__ gi,
                                              const __hip_bfloat16* __restrict__ gh,
                                              const float* __restrict__ msgin,
                                              const float* __restrict__ colsum,
                                              const float* __restrict__ gamma,
                                              const float* __restrict__ beta,
                                              float* __restrict__ out) {
    const int wid = threadIdx.x >> 6;
    const int lane = threadIdx.x & 63;
    const int n = blockIdx.x * 4 + wid;
    if (n >= N_NODES) return;

    const __hip_bfloat16* gir = gi + (size_t)n * 384;
    const __hip_bfloat16* ghr = gh + (size_t)n * 384;

    float hn[2], resid[2];
    float s = 0.f;
#pragma unroll
    for (int t = 0; t < 2; ++t) {
        int c = lane + t * 64;
        float ir = b2f(gir[c]), iz = b2f(gir[128 + c]), inn = b2f(gir[256 + c]);
        float hr = b2f(ghr[c]), hz = b2f(ghr[128 + c]), hhn = b2f(ghr[256 + c]);
        float r = 1.f / (1.f + expf(-(ir + hr)));
        float z = 1.f / (1.f + expf(-(iz + hz)));
        float ng = tanhf(inn + r * hhn);
        float h = nodes[(size_t)n * DIM_H + c];
        hn[t] = (1.f - z) * ng + z * h;
        float mi = msgin[(size_t)n * DIM_H + c];
        resid[t] = mi - colsum[c] * (1.0f / N_NODES);   // recover `messages`
        s += hn[t];
    }
#pragma unroll
    for (int o = 32; o; o >>= 1) s += __shfl_xor(s, o, 64);
    float mu = s * (1.0f / DIM_H);
    float v = 0.f;
#pragma unroll
    for (int t = 0; t < 2; ++t) {
        float d = hn[t] - mu;
        v += d * d;
    }
#pragma unroll
    for (int o = 32; o; o >>= 1) v += __shfl_xor(v, o, 64);
    float rstd = rsqrtf(v * (1.0f / DIM_H) + 1e-5f);
#pragma unroll
    for (int t = 0; t < 2; ++t) {
        int c = lane + t * 64;
        float y = gamma[c] * (hn[t] - mu) * rstd + beta[c];
        out[(size_t)n * DIM_H + c] = y + resid[t];
    }
}

// ---------------------------------------------------------------------------
extern "C" void kernel_launch(void* const* d_in, const int* in_sizes, int n_in,
                              void* d_out, int out_size, void* d_ws, size_t ws_size,
                              hipStream_t stream) {
    const float* nodes = (const float*)d_in[0];
    const float* Wmsg  = (const float*)d_in[1];
    const float* bmsg  = (const float*)d_in[2];
    const float* wih   = (const float*)d_in[3];
    const float* whh   = (const float*)d_in[4];
    const float* bih   = (const float*)d_in[5];
    const float* bhh   = (const float*)d_in[6];
    const float* gamma = (const float*)d_in[7];
    const float* beta  = (const float*)d_in[8];
    const int* esrc = (const int*)d_in[9];
    const int* edst = (const int*)d_in[10];
    float* out = (float*)d_out;

    // workspace layout (f32-aligned): agg | deg | colsum | msgin | gi | gh
    float* agg    = (float*)d_ws;                       // 6,400,000 f32 (25.6 MB)
    float* deg    = agg + (size_t)N_NODES * DIM_H;      // 50,000 f32
    float* colsum = deg + N_NODES;                      // 128 f32
    float* msgin  = colsum + DIM_H;                     // 6,400,000 f32 (25.6 MB)
    __hip_bfloat16* gi = (__hip_bfloat16*)(msgin + (size_t)N_NODES * DIM_H); // 19.2M bf16 (38.4 MB)
    __hip_bfloat16* gh = gi + (size_t)N_NODES * 384;                         // 38.4 MB
    // total ~90.4 MB

    // zero the accumulated regions (ws is poisoned 0xAA before each call)
    hipMemsetAsync(agg, 0, ((size_t)N_NODES * DIM_H + N_NODES + DIM_H) * sizeof(float), stream);

    colsum_k<<<256, 128, 0, stream>>>(nodes, colsum);
    scatter_k<<<N_EDGES / 2, 256, 0, stream>>>(nodes, esrc, edst, agg, deg);

    const int MB = (N_NODES + 63) / 64;  // 782
    // msgin = agg @ Wmsg^T + deg*b_msg + mean
    gemm_k<0><<<dim3(MB, 2), 256, 0, stream>>>(agg, Wmsg, bmsg, deg, colsum,
                                               msgin, nullptr, N_NODES, 128);
    // gi = msgin @ w_ih^T + b_ih
    gemm_k<1><<<dim3(MB, 6), 256, 0, stream>>>(msgin, wih, bih, nullptr, nullptr,
                                               nullptr, gi, N_NODES, 384);
    // gh = nodes @ w_hh^T + b_hh
    gemm_k<2><<<dim3(MB, 6), 256, 0, stream>>>(nodes, whh, bhh, nullptr, nullptr,
                                               nullptr, gh, N_NODES, 384);

    fuse_k<<<(N_NODES + 3) / 4, 256, 0, stream>>>(nodes, gi, gh, msgin, colsum,
                                                  gamma, beta, out);
}

// Round 3
// 690.973 us; speedup vs baseline: 1.2006x; 1.2006x over previous
//
#include <hip/hip_runtime.h>
#include <hip/hip_bf16.h>

#define N_NODES 50000
#define N_EDGES 600000
#define DIM_H   128

__device__ __forceinline__ float b2f(__hip_bfloat16 x) { return __bfloat162float(x); }

// ---------------------------------------------------------------------------
// K1: column sums of nodes (for global mean feature)
// ---------------------------------------------------------------------------
__global__ __launch_bounds__(128) void colsum_k(const float* __restrict__ nodes,
                                                float* __restrict__ colsum) {
    int c = threadIdx.x;               // 0..127
    float s = 0.f;
    for (int r = blockIdx.x; r < N_NODES; r += gridDim.x)
        s += nodes[(size_t)r * DIM_H + c];
    unsafeAtomicAdd(&colsum[c], s);
}

// ---------------------------------------------------------------------------
// CSR build: hist -> scan -> reorder   (counting sort of edges by dst)
// ---------------------------------------------------------------------------
__global__ __launch_bounds__(256) void hist_k(const int* __restrict__ edst,
                                              int* __restrict__ cnt) {
    int e = blockIdx.x * 256 + threadIdx.x;
    if (e < N_EDGES) atomicAdd(&cnt[edst[e]], 1);
}

// single block, 1024 threads: exclusive scan of cnt -> rowptr (and pos copy)
__global__ __launch_bounds__(1024) void scan_k(const int* __restrict__ cnt,
                                               int* __restrict__ rowptr,
                                               int* __restrict__ pos) {
    __shared__ int wsums[16];
    const int tid = threadIdx.x;
    const int lane = tid & 63, wid = tid >> 6;
    int carry = 0;
    for (int base = 0; base < N_NODES; base += 1024) {
        int i = base + tid;
        int v = (i < N_NODES) ? cnt[i] : 0;
        int x = v;
#pragma unroll
        for (int o = 1; o < 64; o <<= 1) {
            int y = __shfl_up(x, o, 64);
            if (lane >= o) x += y;
        }
        if (lane == 63) wsums[wid] = x;
        __syncthreads();
        int woff = 0, total = 0;
#pragma unroll
        for (int w = 0; w < 16; ++w) {
            int s = wsums[w];
            if (w < wid) woff += s;
            total += s;
        }
        int excl = carry + woff + (x - v);
        if (i < N_NODES) { rowptr[i] = excl; pos[i] = excl; }
        carry += total;
        __syncthreads();
    }
    if (tid == 0) rowptr[N_NODES] = carry;
}

__global__ __launch_bounds__(256) void reorder_k(const int* __restrict__ esrc,
                                                 const int* __restrict__ edst,
                                                 int* __restrict__ pos,
                                                 int* __restrict__ ssrc) {
    int e = blockIdx.x * 256 + threadIdx.x;
    if (e < N_EDGES) {
        int p = atomicAdd(&pos[edst[e]], 1);
        ssrc[p] = esrc[e];
    }
}

// ---------------------------------------------------------------------------
// K2': gather-aggregate  agg[n] = sum_{e in row n} nodes[ssrc[e]]
// one wave per node, float2 per lane (512B coalesced row reads)
// ---------------------------------------------------------------------------
__global__ __launch_bounds__(256) void aggregate_k(const float* __restrict__ nodes,
                                                   const int* __restrict__ rowptr,
                                                   const int* __restrict__ ssrc,
                                                   float* __restrict__ agg) {
    const int wid = threadIdx.x >> 6;
    const int lane = threadIdx.x & 63;
    const int n = blockIdx.x * 4 + wid;
    if (n >= N_NODES) return;
    const int s0 = rowptr[n], s1 = rowptr[n + 1];
    float2 acc = {0.f, 0.f};
    int e = s0;
    for (; e + 1 < s1; e += 2) {       // 2 edges/iter for MLP-level ILP
        int sa = ssrc[e], sb = ssrc[e + 1];
        float2 va = ((const float2*)(nodes + (size_t)sa * DIM_H))[lane];
        float2 vb = ((const float2*)(nodes + (size_t)sb * DIM_H))[lane];
        acc.x += va.x + vb.x;
        acc.y += va.y + vb.y;
    }
    if (e < s1) {
        int sa = ssrc[e];
        float2 va = ((const float2*)(nodes + (size_t)sa * DIM_H))[lane];
        acc.x += va.x;
        acc.y += va.y;
    }
    ((float2*)(agg + (size_t)n * DIM_H))[lane] = acc;
}

// ---------------------------------------------------------------------------
// Tiled f32 GEMM: C[M x Nout] = A[M x 128] * W[Nout x 128]^T  (dot over K=128)
// MODE 0: A=agg,   epilogue msgin = C + deg*b_msg + mean   (f32 out)
// MODE 1: A=msgin, epilogue gi = C + b_ih                  (bf16 out)
// MODE 2: A=nodes, epilogue gh = C + b_hh                  (bf16 out)
// ---------------------------------------------------------------------------
template <int MODE>
__global__ __launch_bounds__(256) void gemm_k(const float* __restrict__ A,
                                              const float* __restrict__ W,
                                              const float* __restrict__ bias,
                                              const int* __restrict__ degi,
                                              const float* __restrict__ colsum,
                                              float* __restrict__ out_f,
                                              __hip_bfloat16* __restrict__ out_b,
                                              int M, int Nout) {
    __shared__ float As[128][68];   // As[k][m]
    __shared__ float Ws[128][68];   // Ws[k][n]
    const int tid = threadIdx.x;
    const int m0 = blockIdx.x * 64;
    const int n0 = blockIdx.y * 64;

    for (int i = tid; i < 64 * 128; i += 256) {
        int m = i >> 7, k = i & 127;
        int gm = m0 + m;
        As[k][m] = (gm < M) ? A[(size_t)gm * 128 + k] : 0.f;
    }
    for (int i = tid; i < 64 * 128; i += 256) {
        int n = i >> 7, k = i & 127;
        Ws[k][n] = W[(size_t)(n0 + n) * 128 + k];
    }
    __syncthreads();

    const int tx = tid & 15;   // n-dim (4 cols)
    const int ty = tid >> 4;   // m-dim (4 rows)
    float acc[4][4] = {};
#pragma unroll 4
    for (int k = 0; k < 128; ++k) {
        float4 a = *(const float4*)&As[k][ty * 4];
        float4 b = *(const float4*)&Ws[k][tx * 4];
        float av[4] = {a.x, a.y, a.z, a.w};
        float bv[4] = {b.x, b.y, b.z, b.w};
#pragma unroll
        for (int i = 0; i < 4; ++i)
#pragma unroll
            for (int j = 0; j < 4; ++j)
                acc[i][j] = fmaf(av[i], bv[j], acc[i][j]);
    }

#pragma unroll
    for (int i = 0; i < 4; ++i) {
        int m = m0 + ty * 4 + i;
        if (m < M) {
#pragma unroll
            for (int j = 0; j < 4; ++j) {
                int n = n0 + tx * 4 + j;
                float c = acc[i][j];
                if (MODE == 0) {
                    out_f[(size_t)m * 128 + n] =
                        c + (float)degi[m] * bias[n] + colsum[n] * (1.0f / N_NODES);
                } else {
                    out_b[(size_t)m * Nout + n] = __float2bfloat16(c + bias[n]);
                }
            }
        }
    }
}

// ---------------------------------------------------------------------------
// K5: GRU gates + LayerNorm + residual. One wave (64 lanes) per node.
// ---------------------------------------------------------------------------
__global__ __launch_bounds__(256) void fuse_k(const float* __restrict__ nodes,
                                              const __hip_bfloat16* __restrict__ gi,
                                              const __hip_bfloat16* __restrict__ gh,
                                              const float* __restrict__ msgin,
                                              const float* __restrict__ colsum,
                                              const float* __restrict__ gamma,
                                              const float* __restrict__ beta,
                                              float* __restrict__ out) {
    const int wid = threadIdx.x >> 6;
    const int lane = threadIdx.x & 63;
    const int n = blockIdx.x * 4 + wid;
    if (n >= N_NODES) return;

    const __hip_bfloat16* gir = gi + (size_t)n * 384;
    const __hip_bfloat16* ghr = gh + (size_t)n * 384;

    float hn[2], resid[2];
    float s = 0.f;
#pragma unroll
    for (int t = 0; t < 2; ++t) {
        int c = lane + t * 64;
        float ir = b2f(gir[c]), iz = b2f(gir[128 + c]), inn = b2f(gir[256 + c]);
        float hr = b2f(ghr[c]), hz = b2f(ghr[128 + c]), hhn = b2f(ghr[256 + c]);
        float r = 1.f / (1.f + expf(-(ir + hr)));
        float z = 1.f / (1.f + expf(-(iz + hz)));
        float ng = tanhf(inn + r * hhn);
        float h = nodes[(size_t)n * DIM_H + c];
        hn[t] = (1.f - z) * ng + z * h;
        float mi = msgin[(size_t)n * DIM_H + c];
        resid[t] = mi - colsum[c] * (1.0f / N_NODES);   // recover `messages`
        s += hn[t];
    }
#pragma unroll
    for (int o = 32; o; o >>= 1) s += __shfl_xor(s, o, 64);
    float mu = s * (1.0f / DIM_H);
    float v = 0.f;
#pragma unroll
    for (int t = 0; t < 2; ++t) {
        float d = hn[t] - mu;
        v += d * d;
    }
#pragma unroll
    for (int o = 32; o; o >>= 1) v += __shfl_xor(v, o, 64);
    float rstd = rsqrtf(v * (1.0f / DIM_H) + 1e-5f);
#pragma unroll
    for (int t = 0; t < 2; ++t) {
        int c = lane + t * 64;
        float y = gamma[c] * (hn[t] - mu) * rstd + beta[c];
        out[(size_t)n * DIM_H + c] = y + resid[t];
    }
}

// ---------------------------------------------------------------------------
extern "C" void kernel_launch(void* const* d_in, const int* in_sizes, int n_in,
                              void* d_out, int out_size, void* d_ws, size_t ws_size,
                              hipStream_t stream) {
    const float* nodes = (const float*)d_in[0];
    const float* Wmsg  = (const float*)d_in[1];
    const float* bmsg  = (const float*)d_in[2];
    const float* wih   = (const float*)d_in[3];
    const float* whh   = (const float*)d_in[4];
    const float* bih   = (const float*)d_in[5];
    const float* bhh   = (const float*)d_in[6];
    const float* gamma = (const float*)d_in[7];
    const float* beta  = (const float*)d_in[8];
    const int* esrc = (const int*)d_in[9];
    const int* edst = (const int*)d_in[10];
    float* out = (float*)d_out;

    // workspace layout (~105.4 MB):
    //   R0 [38.4 MB]: agg (f32, 25.6 MB) then gh (bf16) -- stream-ordered alias
    //   R1 [25.6 MB]: msgin (f32)
    //   R2 [38.4 MB]: gi (bf16)
    //   small: colsum | cnt | rowptr | pos | ssrc
    char* ws = (char*)d_ws;
    float* agg            = (float*)ws;                       // R0
    __hip_bfloat16* gh    = (__hip_bfloat16*)ws;              // R0 (after agg is dead)
    float* msgin          = (float*)(ws + 38400000);          // R1
    __hip_bfloat16* gi    = (__hip_bfloat16*)(ws + 64000000); // R2
    float* colsum         = (float*)(ws + 102400000);
    int*   cnt            = (int*)(ws + 102400512);
    int*   rowptr         = cnt + N_NODES;        // N+1
    int*   pos            = rowptr + N_NODES + 1;
    int*   ssrc           = pos + N_NODES;        // N_EDGES

    hipMemsetAsync(cnt, 0, N_NODES * sizeof(int), stream);
    hipMemsetAsync(colsum, 0, DIM_H * sizeof(float), stream);

    colsum_k<<<256, 128, 0, stream>>>(nodes, colsum);

    const int EB = (N_EDGES + 255) / 256;
    hist_k<<<EB, 256, 0, stream>>>(edst, cnt);
    scan_k<<<1, 1024, 0, stream>>>(cnt, rowptr, pos);
    reorder_k<<<EB, 256, 0, stream>>>(esrc, edst, pos, ssrc);
    aggregate_k<<<(N_NODES + 3) / 4, 256, 0, stream>>>(nodes, rowptr, ssrc, agg);

    const int MB = (N_NODES + 63) / 64;  // 782
    // msgin = agg @ Wmsg^T + deg*b_msg + mean
    gemm_k<0><<<dim3(MB, 2), 256, 0, stream>>>(agg, Wmsg, bmsg, cnt, colsum,
                                               msgin, nullptr, N_NODES, 128);
    // gi = msgin @ w_ih^T + b_ih
    gemm_k<1><<<dim3(MB, 6), 256, 0, stream>>>(msgin, wih, bih, nullptr, nullptr,
                                               nullptr, gi, N_NODES, 384);
    // gh = nodes @ w_hh^T + b_hh   (writes R0; agg already consumed by gemm<0>)
    gemm_k<2><<<dim3(MB, 6), 256, 0, stream>>>(nodes, whh, bhh, nullptr, nullptr,
                                               nullptr, gh, N_NODES, 384);

    fuse_k<<<(N_NODES + 3) / 4, 256, 0, stream>>>(nodes, gi, gh, msgin, colsum,
                                                  gamma, beta, out);
}

// Round 4
// 432.247 us; speedup vs baseline: 1.9192x; 1.5986x over previous
//
#include <hip/hip_runtime.h>
#include <hip/hip_bf16.h>

#define N_NODES 50000
#define N_EDGES 600000
#define DIM_H   128

typedef __attribute__((ext_vector_type(8))) short bf16x8;   // 8 bf16 = 4 VGPRs
typedef __attribute__((ext_vector_type(4))) float f32x4;    // MFMA acc
typedef __attribute__((ext_vector_type(4))) short short4v;

__device__ __forceinline__ float b2f(__hip_bfloat16 x) { return __bfloat162float(x); }
__device__ __forceinline__ short f2bs(float f) {
    __hip_bfloat16 h = __float2bfloat16(f);   // RNE
    return *reinterpret_cast<short*>(&h);
}

// ---------------------------------------------------------------------------
// K1: column sums of nodes (for global mean feature)
// ---------------------------------------------------------------------------
__global__ __launch_bounds__(128) void colsum_k(const float* __restrict__ nodes,
                                                float* __restrict__ colsum) {
    int c = threadIdx.x;               // 0..127
    float s = 0.f;
    for (int r = blockIdx.x; r < N_NODES; r += gridDim.x)
        s += nodes[(size_t)r * DIM_H + c];
    unsafeAtomicAdd(&colsum[c], s);
}

// ---------------------------------------------------------------------------
// CSR build: hist -> scan -> reorder   (counting sort of edges by dst)
// ---------------------------------------------------------------------------
__global__ __launch_bounds__(256) void hist_k(const int* __restrict__ edst,
                                              int* __restrict__ cnt) {
    int e = blockIdx.x * 256 + threadIdx.x;
    if (e < N_EDGES) atomicAdd(&cnt[edst[e]], 1);
}

// single block, 1024 threads: exclusive scan of cnt -> rowptr (and pos copy)
__global__ __launch_bounds__(1024) void scan_k(const int* __restrict__ cnt,
                                               int* __restrict__ rowptr,
                                               int* __restrict__ pos) {
    __shared__ int wsums[16];
    const int tid = threadIdx.x;
    const int lane = tid & 63, wid = tid >> 6;
    int carry = 0;
    for (int base = 0; base < N_NODES; base += 1024) {
        int i = base + tid;
        int v = (i < N_NODES) ? cnt[i] : 0;
        int x = v;
#pragma unroll
        for (int o = 1; o < 64; o <<= 1) {
            int y = __shfl_up(x, o, 64);
            if (lane >= o) x += y;
        }
        if (lane == 63) wsums[wid] = x;
        __syncthreads();
        int woff = 0, total = 0;
#pragma unroll
        for (int w = 0; w < 16; ++w) {
            int s = wsums[w];
            if (w < wid) woff += s;
            total += s;
        }
        int excl = carry + woff + (x - v);
        if (i < N_NODES) { rowptr[i] = excl; pos[i] = excl; }
        carry += total;
        __syncthreads();
    }
    if (tid == 0) rowptr[N_NODES] = carry;
}

__global__ __launch_bounds__(256) void reorder_k(const int* __restrict__ esrc,
                                                 const int* __restrict__ edst,
                                                 int* __restrict__ pos,
                                                 int* __restrict__ ssrc) {
    int e = blockIdx.x * 256 + threadIdx.x;
    if (e < N_EDGES) {
        int p = atomicAdd(&pos[edst[e]], 1);
        ssrc[p] = esrc[e];
    }
}

// ---------------------------------------------------------------------------
// K2': gather-aggregate  agg[n] = sum_{e in row n} nodes[ssrc[e]]
// ---------------------------------------------------------------------------
__global__ __launch_bounds__(256) void aggregate_k(const float* __restrict__ nodes,
                                                   const int* __restrict__ rowptr,
                                                   const int* __restrict__ ssrc,
                                                   float* __restrict__ agg) {
    const int wid = threadIdx.x >> 6;
    const int lane = threadIdx.x & 63;
    const int n = blockIdx.x * 4 + wid;
    if (n >= N_NODES) return;
    const int s0 = rowptr[n], s1 = rowptr[n + 1];
    float2 acc = {0.f, 0.f};
    int e = s0;
    for (; e + 1 < s1; e += 2) {
        int sa = ssrc[e], sb = ssrc[e + 1];
        float2 va = ((const float2*)(nodes + (size_t)sa * DIM_H))[lane];
        float2 vb = ((const float2*)(nodes + (size_t)sb * DIM_H))[lane];
        acc.x += va.x + vb.x;
        acc.y += va.y + vb.y;
    }
    if (e < s1) {
        int sa = ssrc[e];
        float2 va = ((const float2*)(nodes + (size_t)sa * DIM_H))[lane];
        acc.x += va.x;
        acc.y += va.y;
    }
    ((float2*)(agg + (size_t)n * DIM_H))[lane] = acc;
}

// ---------------------------------------------------------------------------
// MFMA GEMM: C[M x Nout] = A[M x 128] * W[Nout x 128]^T, bf16 in / f32 acc.
// 128x128 block tile, 4 waves in 2x2, each wave 64x64 via 4x4 16x16x32 MFMAs.
// LDS tiles padded to 136 shorts/row (16B-aligned, quad-bank-group spread).
// MODE 0: epilogue msgin = C + deg*b_msg + mean   (f32 out)
// MODE 1: epilogue gi = C + b_ih                  (bf16 out)
// MODE 2: epilogue gh = C + b_hh                  (bf16 out)
// ---------------------------------------------------------------------------
template <int MODE>
__global__ __launch_bounds__(256) void mgemm_k(const float* __restrict__ A,
                                               const float* __restrict__ W,
                                               const float* __restrict__ bias,
                                               const int* __restrict__ degi,
                                               const float* __restrict__ colsum,
                                               float* __restrict__ out_f,
                                               __hip_bfloat16* __restrict__ out_b,
                                               int M, int Nout) {
    __shared__ short As[128][136];   // [m][k] bf16
    __shared__ short Ws[128][136];   // [n][k] bf16
    const int tid = threadIdx.x;
    const int m0 = blockIdx.x * 128;
    const int n0 = blockIdx.y * 128;

    // stage A: 128 rows x 128 k (f32 -> bf16), float4 per thread-iter
    for (int i = tid; i < 128 * 32; i += 256) {
        int row = i >> 5, q = i & 31;
        int gm = m0 + row;
        short4v s4;
        if (gm < M) {
            float4 v = *(const float4*)(A + (size_t)gm * 128 + q * 4);
            s4 = (short4v){f2bs(v.x), f2bs(v.y), f2bs(v.z), f2bs(v.w)};
        } else {
            s4 = (short4v){0, 0, 0, 0};
        }
        *(short4v*)&As[row][q * 4] = s4;
    }
    // stage W (grid is exact in N; no guard needed)
    for (int i = tid; i < 128 * 32; i += 256) {
        int row = i >> 5, q = i & 31;
        float4 v = *(const float4*)(W + (size_t)(n0 + row) * 128 + q * 4);
        *(short4v*)&Ws[row][q * 4] = (short4v){f2bs(v.x), f2bs(v.y), f2bs(v.z), f2bs(v.w)};
    }
    __syncthreads();

    const int l    = tid & 63;
    const int wv   = tid >> 6;          // 0..3
    const int wm   = (wv >> 1) * 64;    // wave tile origin in M
    const int wn   = (wv & 1) * 64;     // wave tile origin in N
    const int r16  = l & 15;
    const int half = l >> 4;            // 0..3

    f32x4 acc[4][4] = {};
#pragma unroll
    for (int kt = 0; kt < 4; ++kt) {
        const int kb = kt * 32 + half * 8;
        bf16x8 af[4], bf[4];
#pragma unroll
        for (int t = 0; t < 4; ++t) {
            af[t] = *(const bf16x8*)&As[wm + t * 16 + r16][kb];
            bf[t] = *(const bf16x8*)&Ws[wn + t * 16 + r16][kb];
        }
#pragma unroll
        for (int i = 0; i < 4; ++i)
#pragma unroll
            for (int j = 0; j < 4; ++j)
                acc[i][j] = __builtin_amdgcn_mfma_f32_16x16x32_bf16(
                    af[i], bf[j], acc[i][j], 0, 0, 0);
    }

    // epilogue: D[row = half*4 + reg][col = r16] per 16x16 tile
#pragma unroll
    for (int i = 0; i < 4; ++i) {
#pragma unroll
        for (int r = 0; r < 4; ++r) {
            int m = m0 + wm + i * 16 + half * 4 + r;
            if (m < M) {
#pragma unroll
                for (int j = 0; j < 4; ++j) {
                    int n = n0 + wn + j * 16 + r16;
                    float c = acc[i][j][r];
                    if (MODE == 0) {
                        out_f[(size_t)m * 128 + n] =
                            c + (float)degi[m] * bias[n] + colsum[n] * (1.0f / N_NODES);
                    } else {
                        out_b[(size_t)m * Nout + n] = __float2bfloat16(c + bias[n]);
                    }
                }
            }
        }
    }
}

// ---------------------------------------------------------------------------
// K5: GRU gates + LayerNorm + residual. One wave (64 lanes) per node.
// ---------------------------------------------------------------------------
__global__ __launch_bounds__(256) void fuse_k(const float* __restrict__ nodes,
                                              const __hip_bfloat16* __restrict__ gi,
                                              const __hip_bfloat16* __restrict__ gh,
                                              const float* __restrict__ msgin,
                                              const float* __restrict__ colsum,
                                              const float* __restrict__ gamma,
                                              const float* __restrict__ beta,
                                              float* __restrict__ out) {
    const int wid = threadIdx.x >> 6;
    const int lane = threadIdx.x & 63;
    const int n = blockIdx.x * 4 + wid;
    if (n >= N_NODES) return;

    const __hip_bfloat16* gir = gi + (size_t)n * 384;
    const __hip_bfloat16* ghr = gh + (size_t)n * 384;

    float hn[2], resid[2];
    float s = 0.f;
#pragma unroll
    for (int t = 0; t < 2; ++t) {
        int c = lane + t * 64;
        float ir = b2f(gir[c]), iz = b2f(gir[128 + c]), inn = b2f(gir[256 + c]);
        float hr = b2f(ghr[c]), hz = b2f(ghr[128 + c]), hhn = b2f(ghr[256 + c]);
        float r = 1.f / (1.f + expf(-(ir + hr)));
        float z = 1.f / (1.f + expf(-(iz + hz)));
        float ng = tanhf(inn + r * hhn);
        float h = nodes[(size_t)n * DIM_H + c];
        hn[t] = (1.f - z) * ng + z * h;
        float mi = msgin[(size_t)n * DIM_H + c];
        resid[t] = mi - colsum[c] * (1.0f / N_NODES);   // recover `messages`
        s += hn[t];
    }
#pragma unroll
    for (int o = 32; o; o >>= 1) s += __shfl_xor(s, o, 64);
    float mu = s * (1.0f / DIM_H);
    float v = 0.f;
#pragma unroll
    for (int t = 0; t < 2; ++t) {
        float d = hn[t] - mu;
        v += d * d;
    }
#pragma unroll
    for (int o = 32; o; o >>= 1) v += __shfl_xor(v, o, 64);
    float rstd = rsqrtf(v * (1.0f / DIM_H) + 1e-5f);
#pragma unroll
    for (int t = 0; t < 2; ++t) {
        int c = lane + t * 64;
        float y = gamma[c] * (hn[t] - mu) * rstd + beta[c];
        out[(size_t)n * DIM_H + c] = y + resid[t];
    }
}

// ---------------------------------------------------------------------------
extern "C" void kernel_launch(void* const* d_in, const int* in_sizes, int n_in,
                              void* d_out, int out_size, void* d_ws, size_t ws_size,
                              hipStream_t stream) {
    const float* nodes = (const float*)d_in[0];
    const float* Wmsg  = (const float*)d_in[1];
    const float* bmsg  = (const float*)d_in[2];
    const float* wih   = (const float*)d_in[3];
    const float* whh   = (const float*)d_in[4];
    const float* bih   = (const float*)d_in[5];
    const float* bhh   = (const float*)d_in[6];
    const float* gamma = (const float*)d_in[7];
    const float* beta  = (const float*)d_in[8];
    const int* esrc = (const int*)d_in[9];
    const int* edst = (const int*)d_in[10];
    float* out = (float*)d_out;

    // workspace layout (~105.4 MB):
    //   R0 [38.4 MB]: agg (f32, 25.6 MB) then gh (bf16) -- stream-ordered alias
    //   R1 [25.6 MB]: msgin (f32)
    //   R2 [38.4 MB]: gi (bf16)
    //   small: colsum | cnt | rowptr | pos | ssrc
    char* ws = (char*)d_ws;
    float* agg            = (float*)ws;                       // R0
    __hip_bfloat16* gh    = (__hip_bfloat16*)ws;              // R0 (after agg is dead)
    float* msgin          = (float*)(ws + 38400000);          // R1
    __hip_bfloat16* gi    = (__hip_bfloat16*)(ws + 64000000); // R2
    float* colsum         = (float*)(ws + 102400000);
    int*   cnt            = (int*)(ws + 102400512);
    int*   rowptr         = cnt + N_NODES;        // N+1
    int*   pos            = rowptr + N_NODES + 1;
    int*   ssrc           = pos + N_NODES;        // N_EDGES

    hipMemsetAsync(cnt, 0, N_NODES * sizeof(int), stream);
    hipMemsetAsync(colsum, 0, DIM_H * sizeof(float), stream);

    colsum_k<<<256, 128, 0, stream>>>(nodes, colsum);

    const int EB = (N_EDGES + 255) / 256;
    hist_k<<<EB, 256, 0, stream>>>(edst, cnt);
    scan_k<<<1, 1024, 0, stream>>>(cnt, rowptr, pos);
    reorder_k<<<EB, 256, 0, stream>>>(esrc, edst, pos, ssrc);
    aggregate_k<<<(N_NODES + 3) / 4, 256, 0, stream>>>(nodes, rowptr, ssrc, agg);

    const int MB2 = (N_NODES + 127) / 128;  // 391
    // msgin = agg @ Wmsg^T + deg*b_msg + mean
    mgemm_k<0><<<dim3(MB2, 1), 256, 0, stream>>>(agg, Wmsg, bmsg, cnt, colsum,
                                                 msgin, nullptr, N_NODES, 128);
    // gi = msgin @ w_ih^T + b_ih
    mgemm_k<1><<<dim3(MB2, 3), 256, 0, stream>>>(msgin, wih, bih, nullptr, nullptr,
                                                 nullptr, gi, N_NODES, 384);
    // gh = nodes @ w_hh^T + b_hh   (writes R0; agg consumed by mgemm<0>)
    mgemm_k<2><<<dim3(MB2, 3), 256, 0, stream>>>(nodes, whh, bhh, nullptr, nullptr,
                                                 nullptr, gh, N_NODES, 384);

    fuse_k<<<(N_NODES + 3) / 4, 256, 0, stream>>>(nodes, gi, gh, msgin, colsum,
                                                  gamma, beta, out);
}

// Round 5
// 402.415 us; speedup vs baseline: 2.0615x; 1.0741x over previous
//
#include <hip/hip_runtime.h>
#include <hip/hip_bf16.h>

#define N_NODES 50000
#define N_EDGES 600000
#define DIM_H   128

typedef __attribute__((ext_vector_type(8))) short bf16x8;   // 8 bf16 = 4 VGPRs
typedef __attribute__((ext_vector_type(4))) float f32x4;    // MFMA acc
typedef __attribute__((ext_vector_type(4))) short short4v;

__device__ __forceinline__ float b2f(__hip_bfloat16 x) { return __bfloat162float(x); }
__device__ __forceinline__ short f2bs(float f) {
    __hip_bfloat16 h = __float2bfloat16(f);   // RNE
    return *reinterpret_cast<short*>(&h);
}

// ---------------------------------------------------------------------------
// K1: column sums of nodes (for global mean feature)
// 512 blocks x 256 thr; thread = (row-lane rl, col-group cg); float4 loads.
// Old version was latency-bound (2 waves/CU, scalar loads, 208 GB/s).
// ---------------------------------------------------------------------------
__global__ __launch_bounds__(256) void colsum_k(const float* __restrict__ nodes,
                                                float* __restrict__ colsum) {
    __shared__ float red[8][128];
    const int tid = threadIdx.x;
    const int cg = tid & 31;       // column group: cols 4*cg .. 4*cg+3
    const int rl = tid >> 5;       // row lane 0..7
    float4 acc = {0.f, 0.f, 0.f, 0.f};
    for (int r = blockIdx.x * 8 + rl; r < N_NODES; r += gridDim.x * 8) {
        float4 v = *(const float4*)(nodes + (size_t)r * DIM_H + cg * 4);
        acc.x += v.x; acc.y += v.y; acc.z += v.z; acc.w += v.w;
    }
    *(float4*)&red[rl][cg * 4] = acc;
    __syncthreads();
    if (tid < 128) {
        float s = 0.f;
#pragma unroll
        for (int i = 0; i < 8; ++i) s += red[i][tid];
        unsafeAtomicAdd(&colsum[tid], s);
    }
}

// ---------------------------------------------------------------------------
// CSR build: hist -> scan -> reorder   (counting sort of edges by dst)
// ---------------------------------------------------------------------------
__global__ __launch_bounds__(256) void hist_k(const int* __restrict__ edst,
                                              int* __restrict__ cnt) {
    int e = blockIdx.x * 256 + threadIdx.x;
    if (e < N_EDGES) atomicAdd(&cnt[edst[e]], 1);
}

// single block, 1024 threads: exclusive scan of cnt -> rowptr (and pos copy)
__global__ __launch_bounds__(1024) void scan_k(const int* __restrict__ cnt,
                                               int* __restrict__ rowptr,
                                               int* __restrict__ pos) {
    __shared__ int wsums[16];
    const int tid = threadIdx.x;
    const int lane = tid & 63, wid = tid >> 6;
    int carry = 0;
    for (int base = 0; base < N_NODES; base += 1024) {
        int i = base + tid;
        int v = (i < N_NODES) ? cnt[i] : 0;
        int x = v;
#pragma unroll
        for (int o = 1; o < 64; o <<= 1) {
            int y = __shfl_up(x, o, 64);
            if (lane >= o) x += y;
        }
        if (lane == 63) wsums[wid] = x;
        __syncthreads();
        int woff = 0, total = 0;
#pragma unroll
        for (int w = 0; w < 16; ++w) {
            int s = wsums[w];
            if (w < wid) woff += s;
            total += s;
        }
        int excl = carry + woff + (x - v);
        if (i < N_NODES) { rowptr[i] = excl; pos[i] = excl; }
        carry += total;
        __syncthreads();
    }
    if (tid == 0) rowptr[N_NODES] = carry;
}

__global__ __launch_bounds__(256) void reorder_k(const int* __restrict__ esrc,
                                                 const int* __restrict__ edst,
                                                 int* __restrict__ pos,
                                                 int* __restrict__ ssrc) {
    int e = blockIdx.x * 256 + threadIdx.x;
    if (e < N_EDGES) {
        int p = atomicAdd(&pos[edst[e]], 1);
        ssrc[p] = esrc[e];
    }
}

// ---------------------------------------------------------------------------
// K2': gather-aggregate  agg[n] = sum_{e in row n} nodes[ssrc[e]]
// ---------------------------------------------------------------------------
__global__ __launch_bounds__(256) void aggregate_k(const float* __restrict__ nodes,
                                                   const int* __restrict__ rowptr,
                                                   const int* __restrict__ ssrc,
                                                   float* __restrict__ agg) {
    const int wid = threadIdx.x >> 6;
    const int lane = threadIdx.x & 63;
    const int n = blockIdx.x * 4 + wid;
    if (n >= N_NODES) return;
    const int s0 = rowptr[n], s1 = rowptr[n + 1];
    float2 acc = {0.f, 0.f};
    int e = s0;
    for (; e + 1 < s1; e += 2) {
        int sa = ssrc[e], sb = ssrc[e + 1];
        float2 va = ((const float2*)(nodes + (size_t)sa * DIM_H))[lane];
        float2 vb = ((const float2*)(nodes + (size_t)sb * DIM_H))[lane];
        acc.x += va.x + vb.x;
        acc.y += va.y + vb.y;
    }
    if (e < s1) {
        int sa = ssrc[e];
        float2 va = ((const float2*)(nodes + (size_t)sa * DIM_H))[lane];
        acc.x += va.x;
        acc.y += va.y;
    }
    ((float2*)(agg + (size_t)n * DIM_H))[lane] = acc;
}

// ---------------------------------------------------------------------------
// MFMA GEMM: C[M x Nout] = A[M x 128] * W[Nout x 128]^T, bf16 in / f32 acc.
// 128x128 block tile, 4 waves in 2x2, each wave 64x64 via 4x4 16x16x32 MFMAs.
// MODE 0: epilogue msgin = C + deg*b_msg + mean   (f32 out)
// MODE 1: epilogue gi = C + b_ih                  (bf16 out)
// MODE 2: epilogue gh = C + b_hh                  (bf16 out)
// ---------------------------------------------------------------------------
template <int MODE>
__global__ __launch_bounds__(256) void mgemm_k(const float* __restrict__ A,
                                               const float* __restrict__ W,
                                               const float* __restrict__ bias,
                                               const int* __restrict__ degi,
                                               const float* __restrict__ colsum,
                                               float* __restrict__ out_f,
                                               __hip_bfloat16* __restrict__ out_b,
                                               int M, int Nout) {
    __shared__ short As[128][136];   // [m][k] bf16
    __shared__ short Ws[128][136];   // [n][k] bf16
    const int tid = threadIdx.x;
    const int m0 = blockIdx.x * 128;
    const int n0 = blockIdx.y * 128;

    for (int i = tid; i < 128 * 32; i += 256) {
        int row = i >> 5, q = i & 31;
        int gm = m0 + row;
        short4v s4;
        if (gm < M) {
            float4 v = *(const float4*)(A + (size_t)gm * 128 + q * 4);
            s4 = (short4v){f2bs(v.x), f2bs(v.y), f2bs(v.z), f2bs(v.w)};
        } else {
            s4 = (short4v){0, 0, 0, 0};
        }
        *(short4v*)&As[row][q * 4] = s4;
    }
    for (int i = tid; i < 128 * 32; i += 256) {
        int row = i >> 5, q = i & 31;
        float4 v = *(const float4*)(W + (size_t)(n0 + row) * 128 + q * 4);
        *(short4v*)&Ws[row][q * 4] = (short4v){f2bs(v.x), f2bs(v.y), f2bs(v.z), f2bs(v.w)};
    }
    __syncthreads();

    const int l    = tid & 63;
    const int wv   = tid >> 6;          // 0..3
    const int wm   = (wv >> 1) * 64;    // wave tile origin in M
    const int wn   = (wv & 1) * 64;     // wave tile origin in N
    const int r16  = l & 15;
    const int half = l >> 4;            // 0..3

    f32x4 acc[4][4] = {};
#pragma unroll
    for (int kt = 0; kt < 4; ++kt) {
        const int kb = kt * 32 + half * 8;
        bf16x8 af[4], bf[4];
#pragma unroll
        for (int t = 0; t < 4; ++t) {
            af[t] = *(const bf16x8*)&As[wm + t * 16 + r16][kb];
            bf[t] = *(const bf16x8*)&Ws[wn + t * 16 + r16][kb];
        }
#pragma unroll
        for (int i = 0; i < 4; ++i)
#pragma unroll
            for (int j = 0; j < 4; ++j)
                acc[i][j] = __builtin_amdgcn_mfma_f32_16x16x32_bf16(
                    af[i], bf[j], acc[i][j], 0, 0, 0);
    }

    // epilogue: D[row = half*4 + reg][col = r16] per 16x16 tile
#pragma unroll
    for (int i = 0; i < 4; ++i) {
#pragma unroll
        for (int r = 0; r < 4; ++r) {
            int m = m0 + wm + i * 16 + half * 4 + r;
            if (m < M) {
#pragma unroll
                for (int j = 0; j < 4; ++j) {
                    int n = n0 + wn + j * 16 + r16;
                    float c = acc[i][j][r];
                    if (MODE == 0) {
                        out_f[(size_t)m * 128 + n] =
                            c + (float)degi[m] * bias[n] + colsum[n] * (1.0f / N_NODES);
                    } else {
                        out_b[(size_t)m * Nout + n] = __float2bfloat16(c + bias[n]);
                    }
                }
            }
        }
    }
}

// ---------------------------------------------------------------------------
// K5: GRU gates + LayerNorm + residual. One wave (64 lanes) per node.
// ---------------------------------------------------------------------------
__global__ __launch_bounds__(256) void fuse_k(const float* __restrict__ nodes,
                                              const __hip_bfloat16* __restrict__ gi,
                                              const __hip_bfloat16* __restrict__ gh,
                                              const float* __restrict__ msgin,
                                              const float* __restrict__ colsum,
                                              const float* __restrict__ gamma,
                                              const float* __restrict__ beta,
                                              float* __restrict__ out) {
    const int wid = threadIdx.x >> 6;
    const int lane = threadIdx.x & 63;
    const int n = blockIdx.x * 4 + wid;
    if (n >= N_NODES) return;

    const __hip_bfloat16* gir = gi + (size_t)n * 384;
    const __hip_bfloat16* ghr = gh + (size_t)n * 384;

    float hn[2], resid[2];
    float s = 0.f;
#pragma unroll
    for (int t = 0; t < 2; ++t) {
        int c = lane + t * 64;
        float ir = b2f(gir[c]), iz = b2f(gir[128 + c]), inn = b2f(gir[256 + c]);
        float hr = b2f(ghr[c]), hz = b2f(ghr[128 + c]), hhn = b2f(ghr[256 + c]);
        float r = 1.f / (1.f + expf(-(ir + hr)));
        float z = 1.f / (1.f + expf(-(iz + hz)));
        float ng = tanhf(inn + r * hhn);
        float h = nodes[(size_t)n * DIM_H + c];
        hn[t] = (1.f - z) * ng + z * h;
        float mi = msgin[(size_t)n * DIM_H + c];
        resid[t] = mi - colsum[c] * (1.0f / N_NODES);   // recover `messages`
        s += hn[t];
    }
#pragma unroll
    for (int o = 32; o; o >>= 1) s += __shfl_xor(s, o, 64);
    float mu = s * (1.0f / DIM_H);
    float v = 0.f;
#pragma unroll
    for (int t = 0; t < 2; ++t) {
        float d = hn[t] - mu;
        v += d * d;
    }
#pragma unroll
    for (int o = 32; o; o >>= 1) v += __shfl_xor(v, o, 64);
    float rstd = rsqrtf(v * (1.0f / DIM_H) + 1e-5f);
#pragma unroll
    for (int t = 0; t < 2; ++t) {
        int c = lane + t * 64;
        float y = gamma[c] * (hn[t] - mu) * rstd + beta[c];
        out[(size_t)n * DIM_H + c] = y + resid[t];
    }
}

// ---------------------------------------------------------------------------
extern "C" void kernel_launch(void* const* d_in, const int* in_sizes, int n_in,
                              void* d_out, int out_size, void* d_ws, size_t ws_size,
                              hipStream_t stream) {
    const float* nodes = (const float*)d_in[0];
    const float* Wmsg  = (const float*)d_in[1];
    const float* bmsg  = (const float*)d_in[2];
    const float* wih   = (const float*)d_in[3];
    const float* whh   = (const float*)d_in[4];
    const float* bih   = (const float*)d_in[5];
    const float* bhh   = (const float*)d_in[6];
    const float* gamma = (const float*)d_in[7];
    const float* beta  = (const float*)d_in[8];
    const int* esrc = (const int*)d_in[9];
    const int* edst = (const int*)d_in[10];
    float* out = (float*)d_out;

    // workspace layout (~105.4 MB):
    //   R0 [38.4 MB]: agg (f32, 25.6 MB) then gh (bf16) -- stream-ordered alias
    //   R1 [25.6 MB]: msgin (f32)
    //   R2 [38.4 MB]: gi (bf16)
    //   small: colsum | cnt | rowptr | pos | ssrc
    char* ws = (char*)d_ws;
    float* agg            = (float*)ws;                       // R0
    __hip_bfloat16* gh    = (__hip_bfloat16*)ws;              // R0 (after agg is dead)
    float* msgin          = (float*)(ws + 38400000);          // R1
    __hip_bfloat16* gi    = (__hip_bfloat16*)(ws + 64000000); // R2
    float* colsum         = (float*)(ws + 102400000);
    int*   cnt            = (int*)(ws + 102400512);
    int*   rowptr         = cnt + N_NODES;        // N+1
    int*   pos            = rowptr + N_NODES + 1;
    int*   ssrc           = pos + N_NODES;        // N_EDGES

    hipMemsetAsync(cnt, 0, N_NODES * sizeof(int), stream);
    hipMemsetAsync(colsum, 0, DIM_H * sizeof(float), stream);

    colsum_k<<<512, 256, 0, stream>>>(nodes, colsum);

    const int EB = (N_EDGES + 255) / 256;
    hist_k<<<EB, 256, 0, stream>>>(edst, cnt);
    scan_k<<<1, 1024, 0, stream>>>(cnt, rowptr, pos);
    reorder_k<<<EB, 256, 0, stream>>>(esrc, edst, pos, ssrc);
    aggregate_k<<<(N_NODES + 3) / 4, 256, 0, stream>>>(nodes, rowptr, ssrc, agg);

    const int MB2 = (N_NODES + 127) / 128;  // 391
    // msgin = agg @ Wmsg^T + deg*b_msg + mean
    mgemm_k<0><<<dim3(MB2, 1), 256, 0, stream>>>(agg, Wmsg, bmsg, cnt, colsum,
                                                 msgin, nullptr, N_NODES, 128);
    // gi = msgin @ w_ih^T + b_ih
    mgemm_k<1><<<dim3(MB2, 3), 256, 0, stream>>>(msgin, wih, bih, nullptr, nullptr,
                                                 nullptr, gi, N_NODES, 384);
    // gh = nodes @ w_hh^T + b_hh   (writes R0; agg consumed by mgemm<0>)
    mgemm_k<2><<<dim3(MB2, 3), 256, 0, stream>>>(nodes, whh, bhh, nullptr, nullptr,
                                                 nullptr, gh, N_NODES, 384);

    fuse_k<<<(N_NODES + 3) / 4, 256, 0, stream>>>(nodes, gi, gh, msgin, colsum,
                                                  gamma, beta, out);
}

// Round 6
// 340.602 us; speedup vs baseline: 2.4356x; 1.1815x over previous
//
#include <hip/hip_runtime.h>
#include <hip/hip_bf16.h>

#define N_NODES 50000
#define N_EDGES 600000
#define DIM_H   128
#define NPAD    50048   // N_NODES rounded up to 128 (DMA-safe zero tail)

typedef __attribute__((ext_vector_type(8))) short bf16x8;   // 8 bf16 = 4 VGPRs
typedef __attribute__((ext_vector_type(4))) float f32x4;    // MFMA acc
typedef __attribute__((ext_vector_type(4))) short short4v;

__device__ __forceinline__ float b2f(__hip_bfloat16 x) { return __bfloat162float(x); }
__device__ __forceinline__ short f2bs(float f) {
    __hip_bfloat16 h = __float2bfloat16(f);   // RNE
    return *reinterpret_cast<short*>(&h);
}

// global -> LDS async DMA, 16 B per lane; LDS dst is wave-uniform base + lane*16.
// AS3 cast via low-32-bit truncation (LLVM lowers generic->local exactly this way).
__device__ __forceinline__ void dma16(const void* g, const void* lds_uniform) {
    __builtin_amdgcn_global_load_lds(
        (const __attribute__((address_space(1))) void*)g,
        (__attribute__((address_space(3))) void*)(unsigned)(unsigned long long)lds_uniform,
        16, 0, 0);
}

// ---------------------------------------------------------------------------
// K1: column sums of nodes + bf16 copy of nodes (each row visited exactly once)
// ---------------------------------------------------------------------------
__global__ __launch_bounds__(256) void colsum_k(const float* __restrict__ nodes,
                                                float* __restrict__ colsum,
                                                short* __restrict__ nodesB) {
    __shared__ float red[8][128];
    const int tid = threadIdx.x;
    const int cg = tid & 31;       // column group: cols 4*cg .. 4*cg+3
    const int rl = tid >> 5;       // row lane 0..7
    float4 acc = {0.f, 0.f, 0.f, 0.f};
    for (int r = blockIdx.x * 8 + rl; r < N_NODES; r += gridDim.x * 8) {
        float4 v = *(const float4*)(nodes + (size_t)r * DIM_H + cg * 4);
        acc.x += v.x; acc.y += v.y; acc.z += v.z; acc.w += v.w;
        *(short4v*)(nodesB + (size_t)r * DIM_H + cg * 4) =
            (short4v){f2bs(v.x), f2bs(v.y), f2bs(v.z), f2bs(v.w)};
    }
    *(float4*)&red[rl][cg * 4] = acc;
    __syncthreads();
    if (tid < 128) {
        float s = 0.f;
#pragma unroll
        for (int i = 0; i < 8; ++i) s += red[i][tid];
        unsafeAtomicAdd(&colsum[tid], s);
    }
}

// ---------------------------------------------------------------------------
// Weight f32 -> bf16 conversion (wmsg 16384, wih/whh 49152 each)
// ---------------------------------------------------------------------------
__global__ __launch_bounds__(256) void wcvt_k(const float* __restrict__ wmsg,
                                              const float* __restrict__ wih,
                                              const float* __restrict__ whh,
                                              short* __restrict__ wmsgB,
                                              short* __restrict__ wihB,
                                              short* __restrict__ whhB) {
    int i = blockIdx.x * 256 + threadIdx.x;
    if (i < 16384) wmsgB[i] = f2bs(wmsg[i]);
    if (i < 49152) { wihB[i] = f2bs(wih[i]); whhB[i] = f2bs(whh[i]); }
}

// ---------------------------------------------------------------------------
// CSR build: hist -> scan -> reorder   (counting sort of edges by dst)
// ---------------------------------------------------------------------------
__global__ __launch_bounds__(256) void hist_k(const int* __restrict__ edst,
                                              int* __restrict__ cnt) {
    int e = blockIdx.x * 256 + threadIdx.x;
    if (e < N_EDGES) atomicAdd(&cnt[edst[e]], 1);
}

__global__ __launch_bounds__(1024) void scan_k(const int* __restrict__ cnt,
                                               int* __restrict__ rowptr,
                                               int* __restrict__ pos) {
    __shared__ int wsums[16];
    const int tid = threadIdx.x;
    const int lane = tid & 63, wid = tid >> 6;
    int carry = 0;
    for (int base = 0; base < N_NODES; base += 1024) {
        int i = base + tid;
        int v = (i < N_NODES) ? cnt[i] : 0;
        int x = v;
#pragma unroll
        for (int o = 1; o < 64; o <<= 1) {
            int y = __shfl_up(x, o, 64);
            if (lane >= o) x += y;
        }
        if (lane == 63) wsums[wid] = x;
        __syncthreads();
        int woff = 0, total = 0;
#pragma unroll
        for (int w = 0; w < 16; ++w) {
            int s = wsums[w];
            if (w < wid) woff += s;
            total += s;
        }
        int excl = carry + woff + (x - v);
        if (i < N_NODES) { rowptr[i] = excl; pos[i] = excl; }
        carry += total;
        __syncthreads();
    }
    if (tid == 0) rowptr[N_NODES] = carry;
}

__global__ __launch_bounds__(256) void reorder_k(const int* __restrict__ esrc,
                                                 const int* __restrict__ edst,
                                                 int* __restrict__ pos,
                                                 int* __restrict__ ssrc) {
    int e = blockIdx.x * 256 + threadIdx.x;
    if (e < N_EDGES) {
        int p = atomicAdd(&pos[edst[e]], 1);
        ssrc[p] = esrc[e];
    }
}

// ---------------------------------------------------------------------------
// K2': gather-aggregate  aggB[n] = bf16( sum_{e in row n} nodes[ssrc[e]] )
// ---------------------------------------------------------------------------
__global__ __launch_bounds__(256) void aggregate_k(const float* __restrict__ nodes,
                                                   const int* __restrict__ rowptr,
                                                   const int* __restrict__ ssrc,
                                                   short* __restrict__ aggB) {
    const int wid = threadIdx.x >> 6;
    const int lane = threadIdx.x & 63;
    const int n = blockIdx.x * 4 + wid;
    if (n >= N_NODES) return;
    const int s0 = rowptr[n], s1 = rowptr[n + 1];
    float2 acc = {0.f, 0.f};
    int e = s0;
    for (; e + 1 < s1; e += 2) {
        int sa = ssrc[e], sb = ssrc[e + 1];
        float2 va = ((const float2*)(nodes + (size_t)sa * DIM_H))[lane];
        float2 vb = ((const float2*)(nodes + (size_t)sb * DIM_H))[lane];
        acc.x += va.x + vb.x;
        acc.y += va.y + vb.y;
    }
    if (e < s1) {
        int sa = ssrc[e];
        float2 va = ((const float2*)(nodes + (size_t)sa * DIM_H))[lane];
        acc.x += va.x;
        acc.y += va.y;
    }
    short2 o; o.x = f2bs(acc.x); o.y = f2bs(acc.y);
    ((short2*)(aggB + (size_t)n * DIM_H))[lane] = o;
}

// ---------------------------------------------------------------------------
// Shared MFMA tile core: stage A/W bf16 tiles via global_load_lds with XOR-
// swizzled 16B granules (slot q = G ^ (row&15)); 4 waves in 2x2, each 64x64
// via 4x4 16x16x32 bf16 MFMAs. LDS 64 KB -> 2 blocks/CU.
// ---------------------------------------------------------------------------
__device__ __forceinline__ void stage_tile(const short* __restrict__ src, int row0,
                                           short* lds, int w, int lane) {
#pragma unroll
    for (int it = 0; it < 8; ++it) {
        int c = w * 8 + it;
        int s = c * 64 + lane;          // granule slot (16B units)
        int r = s >> 4, q = s & 15;
        int g = q ^ (r & 15);           // which global granule lives in slot q
        dma16(src + (((size_t)(row0 + r)) << 7) + (g << 3), lds + (size_t)c * 512);
    }
}

// msgin GEMM:  msginB = bf16( aggB @ WmsgB^T + deg*b_msg + mean )
__global__ __launch_bounds__(256) void mgemm0_k(const short* __restrict__ aggB,
                                                const short* __restrict__ wmsgB,
                                                const float* __restrict__ bmsg,
                                                const int* __restrict__ degi,
                                                const float* __restrict__ colsum,
                                                short* __restrict__ msginB) {
    __shared__ short As[128 * 128];
    __shared__ short Ws[128 * 128];
    const int tid = threadIdx.x;
    const int lane = tid & 63, w = tid >> 6;
    const int m0 = blockIdx.x * 128;

    stage_tile(aggB, m0, As, w, lane);
    stage_tile(wmsgB, 0, Ws, w, lane);
    __syncthreads();

    const int r16 = lane & 15, half = lane >> 4;
    const int wm = (w >> 1) * 64, wn = (w & 1) * 64;
    f32x4 acc[4][4] = {};
#pragma unroll
    for (int kt = 0; kt < 4; ++kt) {
        const int sq = ((kt * 4 + half) ^ r16) << 3;   // short offset in row
        bf16x8 af[4], bfr[4];
#pragma unroll
        for (int t = 0; t < 4; ++t) {
            af[t]  = *(const bf16x8*)&As[(wm + t * 16 + r16) * 128 + sq];
            bfr[t] = *(const bf16x8*)&Ws[(wn + t * 16 + r16) * 128 + sq];
        }
#pragma unroll
        for (int i = 0; i < 4; ++i)
#pragma unroll
            for (int j = 0; j < 4; ++j)
                acc[i][j] = __builtin_amdgcn_mfma_f32_16x16x32_bf16(
                    af[i], bfr[j], acc[i][j], 0, 0, 0);
    }

#pragma unroll
    for (int i = 0; i < 4; ++i)
#pragma unroll
        for (int r = 0; r < 4; ++r) {
            int m = m0 + wm + i * 16 + half * 4 + r;
            if (m < N_NODES) {
#pragma unroll
                for (int j = 0; j < 4; ++j) {
                    int n = wn + j * 16 + r16;
                    float c = acc[i][j][r] + (float)degi[m] * bmsg[n]
                            + colsum[n] * (1.0f / N_NODES);
                    msginB[(size_t)m * 128 + n] = f2bs(c);
                }
            }
        }
}

// merged gi/gh GEMM: y<3 -> gi = msginB@wihB^T + b_ih ; y>=3 -> gh = nodesB@whhB^T + b_hh
__global__ __launch_bounds__(256) void gigh_k(const short* __restrict__ msginB,
                                              const short* __restrict__ nodesB,
                                              const short* __restrict__ wihB,
                                              const short* __restrict__ whhB,
                                              const float* __restrict__ bih,
                                              const float* __restrict__ bhh,
                                              short* __restrict__ gi,
                                              short* __restrict__ gh) {
    __shared__ short As[128 * 128];
    __shared__ short Ws[128 * 128];
    const int tid = threadIdx.x;
    const int lane = tid & 63, w = tid >> 6;
    const int m0 = blockIdx.x * 128;
    const int y = blockIdx.y;
    const short* A; const short* W; const float* bias; short* out; int n0;
    if (y < 3) { A = msginB; W = wihB; bias = bih; out = gi; n0 = y * 128; }
    else       { A = nodesB; W = whhB; bias = bhh; out = gh; n0 = (y - 3) * 128; }

    stage_tile(A, m0, As, w, lane);
    stage_tile(W, n0, Ws, w, lane);
    __syncthreads();

    const int r16 = lane & 15, half = lane >> 4;
    const int wm = (w >> 1) * 64, wn = (w & 1) * 64;
    f32x4 acc[4][4] = {};
#pragma unroll
    for (int kt = 0; kt < 4; ++kt) {
        const int sq = ((kt * 4 + half) ^ r16) << 3;
        bf16x8 af[4], bfr[4];
#pragma unroll
        for (int t = 0; t < 4; ++t) {
            af[t]  = *(const bf16x8*)&As[(wm + t * 16 + r16) * 128 + sq];
            bfr[t] = *(const bf16x8*)&Ws[(wn + t * 16 + r16) * 128 + sq];
        }
#pragma unroll
        for (int i = 0; i < 4; ++i)
#pragma unroll
            for (int j = 0; j < 4; ++j)
                acc[i][j] = __builtin_amdgcn_mfma_f32_16x16x32_bf16(
                    af[i], bfr[j], acc[i][j], 0, 0, 0);
    }

#pragma unroll
    for (int i = 0; i < 4; ++i)
#pragma unroll
        for (int r = 0; r < 4; ++r) {
            int m = m0 + wm + i * 16 + half * 4 + r;
            if (m < N_NODES) {
#pragma unroll
                for (int j = 0; j < 4; ++j) {
                    int n = n0 + wn + j * 16 + r16;
                    out[(size_t)m * 384 + n] = f2bs(acc[i][j][r] + bias[n]);
                }
            }
        }
}

// ---------------------------------------------------------------------------
// K5: GRU gates + LayerNorm + residual. One wave (64 lanes) per node.
// ---------------------------------------------------------------------------
__global__ __launch_bounds__(256) void fuse_k(const float* __restrict__ nodes,
                                              const __hip_bfloat16* __restrict__ gi,
                                              const __hip_bfloat16* __restrict__ gh,
                                              const __hip_bfloat16* __restrict__ msginB,
                                              const float* __restrict__ colsum,
                                              const float* __restrict__ gamma,
                                              const float* __restrict__ beta,
                                              float* __restrict__ out) {
    const int wid = threadIdx.x >> 6;
    const int lane = threadIdx.x & 63;
    const int n = blockIdx.x * 4 + wid;
    if (n >= N_NODES) return;

    const __hip_bfloat16* gir = gi + (size_t)n * 384;
    const __hip_bfloat16* ghr = gh + (size_t)n * 384;

    float hn[2], resid[2];
    float s = 0.f;
#pragma unroll
    for (int t = 0; t < 2; ++t) {
        int c = lane + t * 64;
        float ir = b2f(gir[c]), iz = b2f(gir[128 + c]), inn = b2f(gir[256 + c]);
        float hr = b2f(ghr[c]), hz = b2f(ghr[128 + c]), hhn = b2f(ghr[256 + c]);
        float r = 1.f / (1.f + expf(-(ir + hr)));
        float z = 1.f / (1.f + expf(-(iz + hz)));
        float ng = tanhf(inn + r * hhn);
        float h = nodes[(size_t)n * DIM_H + c];
        hn[t] = (1.f - z) * ng + z * h;
        float mi = b2f(msginB[(size_t)n * DIM_H + c]);
        resid[t] = mi - colsum[c] * (1.0f / N_NODES);   // recover `messages`
        s += hn[t];
    }
#pragma unroll
    for (int o = 32; o; o >>= 1) s += __shfl_xor(s, o, 64);
    float mu = s * (1.0f / DIM_H);
    float v = 0.f;
#pragma unroll
    for (int t = 0; t < 2; ++t) {
        float d = hn[t] - mu;
        v += d * d;
    }
#pragma unroll
    for (int o = 32; o; o >>= 1) v += __shfl_xor(v, o, 64);
    float rstd = rsqrtf(v * (1.0f / DIM_H) + 1e-5f);
#pragma unroll
    for (int t = 0; t < 2; ++t) {
        int c = lane + t * 64;
        float y = gamma[c] * (hn[t] - mu) * rstd + beta[c];
        out[(size_t)n * DIM_H + c] = y + resid[t];
    }
}

// ---------------------------------------------------------------------------
extern "C" void kernel_launch(void* const* d_in, const int* in_sizes, int n_in,
                              void* d_out, int out_size, void* d_ws, size_t ws_size,
                              hipStream_t stream) {
    const float* nodes = (const float*)d_in[0];
    const float* Wmsg  = (const float*)d_in[1];
    const float* bmsg  = (const float*)d_in[2];
    const float* wih   = (const float*)d_in[3];
    const float* whh   = (const float*)d_in[4];
    const float* bih   = (const float*)d_in[5];
    const float* bhh   = (const float*)d_in[6];
    const float* gamma = (const float*)d_in[7];
    const float* beta  = (const float*)d_in[8];
    const int* esrc = (const int*)d_in[9];
    const int* edst = (const int*)d_in[10];
    float* out = (float*)d_out;

    // workspace layout (~105.7 MB); aggB aliases gi (dead before gi is written)
    char* ws = (char*)d_ws;
    short* gi_s   = (short*)ws;                        // 50000*384*2 = 38.4 MB
    short* aggB   = (short*)ws;                        // NPAD*128*2 = 12.81 MB (alias)
    short* gh_s   = (short*)(ws + 38400000);           // 38.4 MB
    short* nodesB = (short*)(ws + 76800000);           // 12.81 MB (padded)
    short* msginB = (short*)(ws + 89612288);           // 12.81 MB (padded)
    short* wmsgB  = (short*)(ws + 102424576);          // 32 KB
    short* wihB   = (short*)(ws + 102457344);          // 96 KB
    short* whhB   = (short*)(ws + 102555648);          // 96 KB
    float* colsum = (float*)(ws + 102653952);          // 512 B
    int*   cnt    = (int*)(ws + 102654464);            // 200 KB
    int*   rowptr = (int*)(ws + 102854464);            // 200 KB + 4
    int*   pos    = (int*)(ws + 103054472);            // 200 KB
    int*   ssrc   = (int*)(ws + 103254472);            // 2.4 MB -> end ~105.65 MB

    hipMemsetAsync(cnt, 0, N_NODES * sizeof(int), stream);
    hipMemsetAsync(colsum, 0, DIM_H * sizeof(float), stream);
    // zero the 48 padded tail rows of each DMA-read bf16 matrix
    hipMemsetAsync(ws + (size_t)N_NODES * 256, 0, (NPAD - N_NODES) * 256, stream);            // aggB tail
    hipMemsetAsync(ws + 76800000 + (size_t)N_NODES * 256, 0, (NPAD - N_NODES) * 256, stream); // nodesB tail
    hipMemsetAsync(ws + 89612288 + (size_t)N_NODES * 256, 0, (NPAD - N_NODES) * 256, stream); // msginB tail

    colsum_k<<<512, 256, 0, stream>>>(nodes, colsum, nodesB);
    wcvt_k<<<192, 256, 0, stream>>>(Wmsg, wih, whh, wmsgB, wihB, whhB);

    const int EB = (N_EDGES + 255) / 256;
    hist_k<<<EB, 256, 0, stream>>>(edst, cnt);
    scan_k<<<1, 1024, 0, stream>>>(cnt, rowptr, pos);
    reorder_k<<<EB, 256, 0, stream>>>(esrc, edst, pos, ssrc);
    aggregate_k<<<(N_NODES + 3) / 4, 256, 0, stream>>>(nodes, rowptr, ssrc, aggB);

    const int MB2 = (N_NODES + 127) / 128;  // 391
    mgemm0_k<<<dim3(MB2, 1), 256, 0, stream>>>(aggB, wmsgB, bmsg, cnt, colsum, msginB);
    gigh_k<<<dim3(MB2, 6), 256, 0, stream>>>(msginB, nodesB, wihB, whhB, bih, bhh,
                                             gi_s, gh_s);

    fuse_k<<<(N_NODES + 3) / 4, 256, 0, stream>>>(nodes,
                                                  (const __hip_bfloat16*)gi_s,
                                                  (const __hip_bfloat16*)gh_s,
                                                  (const __hip_bfloat16*)msginB,
                                                  colsum, gamma, beta, out);
}

// Round 7
// 299.091 us; speedup vs baseline: 2.7736x; 1.1388x over previous
//
#include <hip/hip_runtime.h>
#include <hip/hip_bf16.h>

#define N_NODES 50000
#define N_EDGES 600000
#define DIM_H   128
#define NPAD    50048   // N_NODES rounded up to 128 (DMA-safe zero tail)
#define NB_SCAN 196     // ceil(N_NODES / 256)

typedef __attribute__((ext_vector_type(8))) short bf16x8;   // 8 bf16 = 4 VGPRs
typedef __attribute__((ext_vector_type(4))) float f32x4;    // MFMA acc
typedef __attribute__((ext_vector_type(4))) short short4v;

__device__ __forceinline__ float b2f(__hip_bfloat16 x) { return __bfloat162float(x); }
__device__ __forceinline__ short f2bs(float f) {
    __hip_bfloat16 h = __float2bfloat16(f);   // RNE
    return *reinterpret_cast<short*>(&h);
}

// global -> LDS async DMA, 16 B per lane; LDS dst is wave-uniform base + lane*16.
__device__ __forceinline__ void dma16(const void* g, const void* lds_uniform) {
    __builtin_amdgcn_global_load_lds(
        (const __attribute__((address_space(1))) void*)g,
        (__attribute__((address_space(3))) void*)(unsigned)(unsigned long long)lds_uniform,
        16, 0, 0);
}

// ---------------------------------------------------------------------------
// K1: column sums of nodes + bf16 copy of nodes (each row visited exactly once)
// ---------------------------------------------------------------------------
__global__ __launch_bounds__(256) void colsum_k(const float* __restrict__ nodes,
                                                float* __restrict__ colsum,
                                                short* __restrict__ nodesB) {
    __shared__ float red[8][128];
    const int tid = threadIdx.x;
    const int cg = tid & 31;       // column group: cols 4*cg .. 4*cg+3
    const int rl = tid >> 5;       // row lane 0..7
    float4 acc = {0.f, 0.f, 0.f, 0.f};
    for (int r = blockIdx.x * 8 + rl; r < N_NODES; r += gridDim.x * 8) {
        float4 v = *(const float4*)(nodes + (size_t)r * DIM_H + cg * 4);
        acc.x += v.x; acc.y += v.y; acc.z += v.z; acc.w += v.w;
        *(short4v*)(nodesB + (size_t)r * DIM_H + cg * 4) =
            (short4v){f2bs(v.x), f2bs(v.y), f2bs(v.z), f2bs(v.w)};
    }
    *(float4*)&red[rl][cg * 4] = acc;
    __syncthreads();
    if (tid < 128) {
        float s = 0.f;
#pragma unroll
        for (int i = 0; i < 8; ++i) s += red[i][tid];
        unsafeAtomicAdd(&colsum[tid], s);
    }
}

// ---------------------------------------------------------------------------
// Weight f32 -> bf16 conversion
// ---------------------------------------------------------------------------
__global__ __launch_bounds__(256) void wcvt_k(const float* __restrict__ wmsg,
                                              const float* __restrict__ wih,
                                              const float* __restrict__ whh,
                                              short* __restrict__ wmsgB,
                                              short* __restrict__ wihB,
                                              short* __restrict__ whhB) {
    int i = blockIdx.x * 256 + threadIdx.x;
    if (i < 16384) wmsgB[i] = f2bs(wmsg[i]);
    if (i < 49152) { wihB[i] = f2bs(wih[i]); whhB[i] = f2bs(whh[i]); }
}

// ---------------------------------------------------------------------------
// CSR build: hist -> (bsum, scan2) -> reorder   (counting sort by dst)
// ---------------------------------------------------------------------------
__global__ __launch_bounds__(256) void hist_k(const int* __restrict__ edst,
                                              int* __restrict__ cnt) {
    int e = blockIdx.x * 256 + threadIdx.x;
    if (e < N_EDGES) atomicAdd(&cnt[edst[e]], 1);
}

// per-256-chunk sums of cnt
__global__ __launch_bounds__(256) void bsum_k(const int* __restrict__ cnt,
                                              int* __restrict__ bsum) {
    const int t = threadIdx.x;
    int i = blockIdx.x * 256 + t;
    int v = (i < N_NODES) ? cnt[i] : 0;
#pragma unroll
    for (int o = 32; o; o >>= 1) v += __shfl_xor(v, o, 64);
    __shared__ int w4[4];
    if ((t & 63) == 0) w4[t >> 6] = v;
    __syncthreads();
    if (t == 0) bsum[blockIdx.x] = w4[0] + w4[1] + w4[2] + w4[3];
}

// per-chunk exclusive scan + global offset from bsum (NB_SCAN <= 256)
__global__ __launch_bounds__(256) void scan2_k(const int* __restrict__ cnt,
                                               const int* __restrict__ bsum,
                                               int* __restrict__ rowptr,
                                               int* __restrict__ pos) {
    const int b = blockIdx.x, t = threadIdx.x;
    const int lane = t & 63, w = t >> 6;
    __shared__ int red[4];
    __shared__ int wsum[4];

    // offset = sum_{j<b} bsum[j]
    int ov = (t < b) ? bsum[t] : 0;
#pragma unroll
    for (int o = 32; o; o >>= 1) ov += __shfl_xor(ov, o, 64);
    if (lane == 0) red[w] = ov;
    __syncthreads();
    const int offset = red[0] + red[1] + red[2] + red[3];

    int i = b * 256 + t;
    int v = (i < N_NODES) ? cnt[i] : 0;
    int x = v;
#pragma unroll
    for (int o = 1; o < 64; o <<= 1) {
        int y = __shfl_up(x, o, 64);
        if (lane >= o) x += y;
    }
    if (lane == 63) wsum[w] = x;
    __syncthreads();
    int woff = 0;
#pragma unroll
    for (int j = 0; j < 4; ++j)
        if (j < w) woff += wsum[j];
    int excl = offset + woff + (x - v);
    if (i < N_NODES) { rowptr[i] = excl; pos[i] = excl; }
    if (i == N_NODES - 1) rowptr[N_NODES] = excl + v;
}

__global__ __launch_bounds__(256) void reorder_k(const int* __restrict__ esrc,
                                                 const int* __restrict__ edst,
                                                 int* __restrict__ pos,
                                                 int* __restrict__ ssrc) {
    int e = blockIdx.x * 256 + threadIdx.x;
    if (e < N_EDGES) {
        int p = atomicAdd(&pos[edst[e]], 1);
        ssrc[p] = esrc[e];
    }
}

// ---------------------------------------------------------------------------
// K2': gather-aggregate  aggB[n] = bf16( sum_{e in row n} nodes[ssrc[e]] )
// ---------------------------------------------------------------------------
__global__ __launch_bounds__(256) void aggregate_k(const float* __restrict__ nodes,
                                                   const int* __restrict__ rowptr,
                                                   const int* __restrict__ ssrc,
                                                   short* __restrict__ aggB) {
    const int wid = threadIdx.x >> 6;
    const int lane = threadIdx.x & 63;
    const int n = blockIdx.x * 4 + wid;
    if (n >= N_NODES) return;
    const int s0 = rowptr[n], s1 = rowptr[n + 1];
    float2 acc = {0.f, 0.f};
    int e = s0;
    for (; e + 1 < s1; e += 2) {
        int sa = ssrc[e], sb = ssrc[e + 1];
        float2 va = ((const float2*)(nodes + (size_t)sa * DIM_H))[lane];
        float2 vb = ((const float2*)(nodes + (size_t)sb * DIM_H))[lane];
        acc.x += va.x + vb.x;
        acc.y += va.y + vb.y;
    }
    if (e < s1) {
        int sa = ssrc[e];
        float2 va = ((const float2*)(nodes + (size_t)sa * DIM_H))[lane];
        acc.x += va.x;
        acc.y += va.y;
    }
    short2 o; o.x = f2bs(acc.x); o.y = f2bs(acc.y);
    ((short2*)(aggB + (size_t)n * DIM_H))[lane] = o;
}

// ---------------------------------------------------------------------------
// Shared MFMA tile core: stage A/W bf16 tiles via global_load_lds with XOR-
// swizzled 16B granules (slot q = G ^ (row&15)); 4 waves in 2x2, each 64x64
// via 4x4 16x16x32 bf16 MFMAs.
// ---------------------------------------------------------------------------
__device__ __forceinline__ void stage_tile(const short* __restrict__ src, int row0,
                                           short* lds, int w, int lane) {
#pragma unroll
    for (int it = 0; it < 8; ++it) {
        int c = w * 8 + it;
        int s = c * 64 + lane;          // granule slot (16B units)
        int r = s >> 4, q = s & 15;
        int g = q ^ (r & 15);           // which global granule lives in slot q
        dma16(src + (((size_t)(row0 + r)) << 7) + (g << 3), lds + (size_t)c * 512);
    }
}

// msgin GEMM:  msginB = bf16( aggB @ WmsgB^T + deg*b_msg + mean )
__global__ __launch_bounds__(256) void mgemm0_k(const short* __restrict__ aggB,
                                                const short* __restrict__ wmsgB,
                                                const float* __restrict__ bmsg,
                                                const int* __restrict__ degi,
                                                const float* __restrict__ colsum,
                                                short* __restrict__ msginB) {
    __shared__ short As[128 * 128];
    __shared__ short Ws[128 * 128];
    const int tid = threadIdx.x;
    const int lane = tid & 63, w = tid >> 6;
    const int m0 = blockIdx.x * 128;

    stage_tile(aggB, m0, As, w, lane);
    stage_tile(wmsgB, 0, Ws, w, lane);
    __syncthreads();

    const int r16 = lane & 15, half = lane >> 4;
    const int wm = (w >> 1) * 64, wn = (w & 1) * 64;
    f32x4 acc[4][4] = {};
#pragma unroll
    for (int kt = 0; kt < 4; ++kt) {
        const int sq = ((kt * 4 + half) ^ r16) << 3;   // short offset in row
        bf16x8 af[4], bfr[4];
#pragma unroll
        for (int t = 0; t < 4; ++t) {
            af[t]  = *(const bf16x8*)&As[(wm + t * 16 + r16) * 128 + sq];
            bfr[t] = *(const bf16x8*)&Ws[(wn + t * 16 + r16) * 128 + sq];
        }
#pragma unroll
        for (int i = 0; i < 4; ++i)
#pragma unroll
            for (int j = 0; j < 4; ++j)
                acc[i][j] = __builtin_amdgcn_mfma_f32_16x16x32_bf16(
                    af[i], bfr[j], acc[i][j], 0, 0, 0);
    }

#pragma unroll
    for (int i = 0; i < 4; ++i)
#pragma unroll
        for (int r = 0; r < 4; ++r) {
            int m = m0 + wm + i * 16 + half * 4 + r;
            if (m < N_NODES) {
#pragma unroll
                for (int j = 0; j < 4; ++j) {
                    int n = wn + j * 16 + r16;
                    float c = acc[i][j][r] + (float)degi[m] * bmsg[n]
                            + colsum[n] * (1.0f / N_NODES);
                    msginB[(size_t)m * 128 + n] = f2bs(c);
                }
            }
        }
}

// merged gi/gh GEMM: y<3 -> gi = msginB@wihB^T + b_ih ; y>=3 -> gh = nodesB@whhB^T + b_hh
__global__ __launch_bounds__(256) void gigh_k(const short* __restrict__ msginB,
                                              const short* __restrict__ nodesB,
                                              const short* __restrict__ wihB,
                                              const short* __restrict__ whhB,
                                              const float* __restrict__ bih,
                                              const float* __restrict__ bhh,
                                              short* __restrict__ gi,
                                              short* __restrict__ gh) {
    __shared__ short As[128 * 128];
    __shared__ short Ws[128 * 128];
    const int tid = threadIdx.x;
    const int lane = tid & 63, w = tid >> 6;
    const int m0 = blockIdx.x * 128;
    const int y = blockIdx.y;
    const short* A; const short* W; const float* bias; short* out; int n0;
    if (y < 3) { A = msginB; W = wihB; bias = bih; out = gi; n0 = y * 128; }
    else       { A = nodesB; W = whhB; bias = bhh; out = gh; n0 = (y - 3) * 128; }

    stage_tile(A, m0, As, w, lane);
    stage_tile(W, n0, Ws, w, lane);
    __syncthreads();

    const int r16 = lane & 15, half = lane >> 4;
    const int wm = (w >> 1) * 64, wn = (w & 1) * 64;
    f32x4 acc[4][4] = {};
#pragma unroll
    for (int kt = 0; kt < 4; ++kt) {
        const int sq = ((kt * 4 + half) ^ r16) << 3;
        bf16x8 af[4], bfr[4];
#pragma unroll
        for (int t = 0; t < 4; ++t) {
            af[t]  = *(const bf16x8*)&As[(wm + t * 16 + r16) * 128 + sq];
            bfr[t] = *(const bf16x8*)&Ws[(wn + t * 16 + r16) * 128 + sq];
        }
#pragma unroll
        for (int i = 0; i < 4; ++i)
#pragma unroll
            for (int j = 0; j < 4; ++j)
                acc[i][j] = __builtin_amdgcn_mfma_f32_16x16x32_bf16(
                    af[i], bfr[j], acc[i][j], 0, 0, 0);
    }

#pragma unroll
    for (int i = 0; i < 4; ++i)
#pragma unroll
        for (int r = 0; r < 4; ++r) {
            int m = m0 + wm + i * 16 + half * 4 + r;
            if (m < N_NODES) {
#pragma unroll
                for (int j = 0; j < 4; ++j) {
                    int n = n0 + wn + j * 16 + r16;
                    out[(size_t)m * 384 + n] = f2bs(acc[i][j][r] + bias[n]);
                }
            }
        }
}

// ---------------------------------------------------------------------------
// K5: GRU gates + LayerNorm + residual. One wave (64 lanes) per node.
// ---------------------------------------------------------------------------
__global__ __launch_bounds__(256) void fuse_k(const float* __restrict__ nodes,
                                              const __hip_bfloat16* __restrict__ gi,
                                              const __hip_bfloat16* __restrict__ gh,
                                              const __hip_bfloat16* __restrict__ msginB,
                                              const float* __restrict__ colsum,
                                              const float* __restrict__ gamma,
                                              const float* __restrict__ beta,
                                              float* __restrict__ out) {
    const int wid = threadIdx.x >> 6;
    const int lane = threadIdx.x & 63;
    const int n = blockIdx.x * 4 + wid;
    if (n >= N_NODES) return;

    const __hip_bfloat16* gir = gi + (size_t)n * 384;
    const __hip_bfloat16* ghr = gh + (size_t)n * 384;

    float hn[2], resid[2];
    float s = 0.f;
#pragma unroll
    for (int t = 0; t < 2; ++t) {
        int c = lane + t * 64;
        float ir = b2f(gir[c]), iz = b2f(gir[128 + c]), inn = b2f(gir[256 + c]);
        float hr = b2f(ghr[c]), hz = b2f(ghr[128 + c]), hhn = b2f(ghr[256 + c]);
        float r = 1.f / (1.f + expf(-(ir + hr)));
        float z = 1.f / (1.f + expf(-(iz + hz)));
        float ng = tanhf(inn + r * hhn);
        float h = nodes[(size_t)n * DIM_H + c];
        hn[t] = (1.f - z) * ng + z * h;
        float mi = b2f(msginB[(size_t)n * DIM_H + c]);
        resid[t] = mi - colsum[c] * (1.0f / N_NODES);   // recover `messages`
        s += hn[t];
    }
#pragma unroll
    for (int o = 32; o; o >>= 1) s += __shfl_xor(s, o, 64);
    float mu = s * (1.0f / DIM_H);
    float v = 0.f;
#pragma unroll
    for (int t = 0; t < 2; ++t) {
        float d = hn[t] - mu;
        v += d * d;
    }
#pragma unroll
    for (int o = 32; o; o >>= 1) v += __shfl_xor(v, o, 64);
    float rstd = rsqrtf(v * (1.0f / DIM_H) + 1e-5f);
#pragma unroll
    for (int t = 0; t < 2; ++t) {
        int c = lane + t * 64;
        float y = gamma[c] * (hn[t] - mu) * rstd + beta[c];
        out[(size_t)n * DIM_H + c] = y + resid[t];
    }
}

// ---------------------------------------------------------------------------
extern "C" void kernel_launch(void* const* d_in, const int* in_sizes, int n_in,
                              void* d_out, int out_size, void* d_ws, size_t ws_size,
                              hipStream_t stream) {
    const float* nodes = (const float*)d_in[0];
    const float* Wmsg  = (const float*)d_in[1];
    const float* bmsg  = (const float*)d_in[2];
    const float* wih   = (const float*)d_in[3];
    const float* whh   = (const float*)d_in[4];
    const float* bih   = (const float*)d_in[5];
    const float* bhh   = (const float*)d_in[6];
    const float* gamma = (const float*)d_in[7];
    const float* beta  = (const float*)d_in[8];
    const int* esrc = (const int*)d_in[9];
    const int* edst = (const int*)d_in[10];
    float* out = (float*)d_out;

    // workspace layout (~105.7 MB); aggB aliases gi (dead before gi is written),
    // bsum aliases head of gh (dead until gigh_k, long after scan2_k)
    char* ws = (char*)d_ws;
    short* gi_s   = (short*)ws;                        // 50000*384*2 = 38.4 MB
    short* aggB   = (short*)ws;                        // NPAD*128*2 = 12.81 MB (alias)
    short* gh_s   = (short*)(ws + 38400000);           // 38.4 MB
    int*   bsum   = (int*)(ws + 38400000);             // 784 B (alias, dead pre-gigh)
    short* nodesB = (short*)(ws + 76800000);           // 12.81 MB (padded)
    short* msginB = (short*)(ws + 89612288);           // 12.81 MB (padded)
    short* wmsgB  = (short*)(ws + 102424576);          // 32 KB
    short* wihB   = (short*)(ws + 102457344);          // 96 KB
    short* whhB   = (short*)(ws + 102555648);          // 96 KB
    float* colsum = (float*)(ws + 102653952);          // 512 B
    int*   cnt    = (int*)(ws + 102654464);            // 200 KB
    int*   rowptr = (int*)(ws + 102854464);            // 200 KB + 4
    int*   pos    = (int*)(ws + 103054472);            // 200 KB
    int*   ssrc   = (int*)(ws + 103254472);            // 2.4 MB -> end ~105.65 MB

    hipMemsetAsync(cnt, 0, N_NODES * sizeof(int), stream);
    hipMemsetAsync(colsum, 0, DIM_H * sizeof(float), stream);
    // zero the 48 padded tail rows of each DMA-read bf16 matrix
    hipMemsetAsync(ws + (size_t)N_NODES * 256, 0, (NPAD - N_NODES) * 256, stream);            // aggB tail
    hipMemsetAsync(ws + 76800000 + (size_t)N_NODES * 256, 0, (NPAD - N_NODES) * 256, stream); // nodesB tail
    hipMemsetAsync(ws + 89612288 + (size_t)N_NODES * 256, 0, (NPAD - N_NODES) * 256, stream); // msginB tail

    colsum_k<<<512, 256, 0, stream>>>(nodes, colsum, nodesB);
    wcvt_k<<<192, 256, 0, stream>>>(Wmsg, wih, whh, wmsgB, wihB, whhB);

    const int EB = (N_EDGES + 255) / 256;
    hist_k<<<EB, 256, 0, stream>>>(edst, cnt);
    bsum_k<<<NB_SCAN, 256, 0, stream>>>(cnt, bsum);
    scan2_k<<<NB_SCAN, 256, 0, stream>>>(cnt, bsum, rowptr, pos);
    reorder_k<<<EB, 256, 0, stream>>>(esrc, edst, pos, ssrc);
    aggregate_k<<<(N_NODES + 3) / 4, 256, 0, stream>>>(nodes, rowptr, ssrc, aggB);

    const int MB2 = (N_NODES + 127) / 128;  // 391
    mgemm0_k<<<dim3(MB2, 1), 256, 0, stream>>>(aggB, wmsgB, bmsg, cnt, colsum, msginB);
    gigh_k<<<dim3(MB2, 6), 256, 0, stream>>>(msginB, nodesB, wihB, whhB, bih, bhh,
                                             gi_s, gh_s);

    fuse_k<<<(N_NODES + 3) / 4, 256, 0, stream>>>(nodes,
                                                  (const __hip_bfloat16*)gi_s,
                                                  (const __hip_bfloat16*)gh_s,
                                                  (const __hip_bfloat16*)msginB,
                                                  colsum, gamma, beta, out);
}

// Round 8
// 281.073 us; speedup vs baseline: 2.9514x; 1.0641x over previous
//
#include <hip/hip_runtime.h>
#include <hip/hip_bf16.h>

#define N_NODES 50000
#define N_EDGES 600000
#define DIM_H   128
#define NPAD    50048   // N_NODES rounded up to 128 (DMA-safe zero tail)
#define NB_SCAN 196     // ceil(N_NODES / 256)

typedef __attribute__((ext_vector_type(8))) short bf16x8;   // 8 bf16 = 4 VGPRs
typedef __attribute__((ext_vector_type(4))) float f32x4;    // MFMA acc
typedef __attribute__((ext_vector_type(4))) short short4v;

__device__ __forceinline__ float b2f(__hip_bfloat16 x) { return __bfloat162float(x); }
__device__ __forceinline__ short f2bs(float f) {
    __hip_bfloat16 h = __float2bfloat16(f);   // RNE
    return *reinterpret_cast<short*>(&h);
}
__device__ __forceinline__ float bs2f(short s) {
    unsigned u = ((unsigned)(unsigned short)s) << 16;
    return __builtin_bit_cast(float, u);
}

// global -> LDS async DMA, 16 B per lane; LDS dst is wave-uniform base + lane*16.
__device__ __forceinline__ void dma16(const void* g, const void* lds_uniform) {
    __builtin_amdgcn_global_load_lds(
        (const __attribute__((address_space(1))) void*)g,
        (__attribute__((address_space(3))) void*)(unsigned)(unsigned long long)lds_uniform,
        16, 0, 0);
}

// ---------------------------------------------------------------------------
// K1: column sums of nodes + bf16 copy of nodes (each row visited exactly once)
// ---------------------------------------------------------------------------
__global__ __launch_bounds__(256) void colsum_k(const float* __restrict__ nodes,
                                                float* __restrict__ colsum,
                                                short* __restrict__ nodesB) {
    __shared__ float red[8][128];
    const int tid = threadIdx.x;
    const int cg = tid & 31;       // column group: cols 4*cg .. 4*cg+3
    const int rl = tid >> 5;       // row lane 0..7
    float4 acc = {0.f, 0.f, 0.f, 0.f};
    for (int r = blockIdx.x * 8 + rl; r < N_NODES; r += gridDim.x * 8) {
        float4 v = *(const float4*)(nodes + (size_t)r * DIM_H + cg * 4);
        acc.x += v.x; acc.y += v.y; acc.z += v.z; acc.w += v.w;
        *(short4v*)(nodesB + (size_t)r * DIM_H + cg * 4) =
            (short4v){f2bs(v.x), f2bs(v.y), f2bs(v.z), f2bs(v.w)};
    }
    *(float4*)&red[rl][cg * 4] = acc;
    __syncthreads();
    if (tid < 128) {
        float s = 0.f;
#pragma unroll
        for (int i = 0; i < 8; ++i) s += red[i][tid];
        unsafeAtomicAdd(&colsum[tid], s);
    }
}

// ---------------------------------------------------------------------------
// Weight f32 -> bf16 conversion
// ---------------------------------------------------------------------------
__global__ __launch_bounds__(256) void wcvt_k(const float* __restrict__ wmsg,
                                              const float* __restrict__ wih,
                                              const float* __restrict__ whh,
                                              short* __restrict__ wmsgB,
                                              short* __restrict__ wihB,
                                              short* __restrict__ whhB) {
    int i = blockIdx.x * 256 + threadIdx.x;
    if (i < 16384) wmsgB[i] = f2bs(wmsg[i]);
    if (i < 49152) { wihB[i] = f2bs(wih[i]); whhB[i] = f2bs(whh[i]); }
}

// ---------------------------------------------------------------------------
// CSR build: hist -> (bsum, scan2) -> reorder   (counting sort by dst)
// ---------------------------------------------------------------------------
__global__ __launch_bounds__(256) void hist_k(const int* __restrict__ edst,
                                              int* __restrict__ cnt) {
    int e = blockIdx.x * 256 + threadIdx.x;
    if (e < N_EDGES) atomicAdd(&cnt[edst[e]], 1);
}

// per-256-chunk sums of cnt
__global__ __launch_bounds__(256) void bsum_k(const int* __restrict__ cnt,
                                              int* __restrict__ bsum) {
    const int t = threadIdx.x;
    int i = blockIdx.x * 256 + t;
    int v = (i < N_NODES) ? cnt[i] : 0;
#pragma unroll
    for (int o = 32; o; o >>= 1) v += __shfl_xor(v, o, 64);
    __shared__ int w4[4];
    if ((t & 63) == 0) w4[t >> 6] = v;
    __syncthreads();
    if (t == 0) bsum[blockIdx.x] = w4[0] + w4[1] + w4[2] + w4[3];
}

// per-chunk exclusive scan + global offset from bsum (NB_SCAN <= 256)
__global__ __launch_bounds__(256) void scan2_k(const int* __restrict__ cnt,
                                               const int* __restrict__ bsum,
                                               int* __restrict__ rowptr,
                                               int* __restrict__ pos) {
    const int b = blockIdx.x, t = threadIdx.x;
    const int lane = t & 63, w = t >> 6;
    __shared__ int red[4];
    __shared__ int wsum[4];

    // offset = sum_{j<b} bsum[j]
    int ov = (t < b) ? bsum[t] : 0;
#pragma unroll
    for (int o = 32; o; o >>= 1) ov += __shfl_xor(ov, o, 64);
    if (lane == 0) red[w] = ov;
    __syncthreads();
    const int offset = red[0] + red[1] + red[2] + red[3];

    int i = b * 256 + t;
    int v = (i < N_NODES) ? cnt[i] : 0;
    int x = v;
#pragma unroll
    for (int o = 1; o < 64; o <<= 1) {
        int y = __shfl_up(x, o, 64);
        if (lane >= o) x += y;
    }
    if (lane == 63) wsum[w] = x;
    __syncthreads();
    int woff = 0;
#pragma unroll
    for (int j = 0; j < 4; ++j)
        if (j < w) woff += wsum[j];
    int excl = offset + woff + (x - v);
    if (i < N_NODES) { rowptr[i] = excl; pos[i] = excl; }
    if (i == N_NODES - 1) rowptr[N_NODES] = excl + v;
}

__global__ __launch_bounds__(256) void reorder_k(const int* __restrict__ esrc,
                                                 const int* __restrict__ edst,
                                                 int* __restrict__ pos,
                                                 int* __restrict__ ssrc) {
    int e = blockIdx.x * 256 + threadIdx.x;
    if (e < N_EDGES) {
        int p = atomicAdd(&pos[edst[e]], 1);
        ssrc[p] = esrc[e];
    }
}

// ---------------------------------------------------------------------------
// K2': gather-aggregate  aggB[n] = bf16( sum_{e in row n} nodesB[ssrc[e]] )
// bf16 gather (256 B/row) halves the 307 MB f32 gather volume; f32 accumulate.
// ---------------------------------------------------------------------------
__global__ __launch_bounds__(256) void aggregate_k(const short* __restrict__ nodesB,
                                                   const int* __restrict__ rowptr,
                                                   const int* __restrict__ ssrc,
                                                   short* __restrict__ aggB) {
    const int wid = threadIdx.x >> 6;
    const int lane = threadIdx.x & 63;
    const int n = blockIdx.x * 4 + wid;
    if (n >= N_NODES) return;
    const int s0 = rowptr[n], s1 = rowptr[n + 1];
    float2 acc = {0.f, 0.f};
    int e = s0;
    for (; e + 3 < s1; e += 4) {       // 4 edges in flight per lane
        int sa = ssrc[e], sb = ssrc[e + 1], sc = ssrc[e + 2], sd = ssrc[e + 3];
        short2 va = ((const short2*)(nodesB + (size_t)sa * DIM_H))[lane];
        short2 vb = ((const short2*)(nodesB + (size_t)sb * DIM_H))[lane];
        short2 vc = ((const short2*)(nodesB + (size_t)sc * DIM_H))[lane];
        short2 vd = ((const short2*)(nodesB + (size_t)sd * DIM_H))[lane];
        acc.x += (bs2f(va.x) + bs2f(vb.x)) + (bs2f(vc.x) + bs2f(vd.x));
        acc.y += (bs2f(va.y) + bs2f(vb.y)) + (bs2f(vc.y) + bs2f(vd.y));
    }
    for (; e < s1; ++e) {
        int sa = ssrc[e];
        short2 va = ((const short2*)(nodesB + (size_t)sa * DIM_H))[lane];
        acc.x += bs2f(va.x);
        acc.y += bs2f(va.y);
    }
    short2 o; o.x = f2bs(acc.x); o.y = f2bs(acc.y);
    ((short2*)(aggB + (size_t)n * DIM_H))[lane] = o;
}

// ---------------------------------------------------------------------------
// Shared MFMA tile core: stage A/W bf16 tiles via global_load_lds with XOR-
// swizzled 16B granules (slot q = G ^ (row&15)); 4 waves in 2x2, each 64x64
// via 4x4 16x16x32 bf16 MFMAs.
// ---------------------------------------------------------------------------
__device__ __forceinline__ void stage_tile(const short* __restrict__ src, int row0,
                                           short* lds, int w, int lane) {
#pragma unroll
    for (int it = 0; it < 8; ++it) {
        int c = w * 8 + it;
        int s = c * 64 + lane;          // granule slot (16B units)
        int r = s >> 4, q = s & 15;
        int g = q ^ (r & 15);           // which global granule lives in slot q
        dma16(src + (((size_t)(row0 + r)) << 7) + (g << 3), lds + (size_t)c * 512);
    }
}

// msgin GEMM:  msginB = bf16( aggB @ WmsgB^T + deg*b_msg + mean )
__global__ __launch_bounds__(256) void mgemm0_k(const short* __restrict__ aggB,
                                                const short* __restrict__ wmsgB,
                                                const float* __restrict__ bmsg,
                                                const int* __restrict__ degi,
                                                const float* __restrict__ colsum,
                                                short* __restrict__ msginB) {
    __shared__ short As[128 * 128];
    __shared__ short Ws[128 * 128];
    const int tid = threadIdx.x;
    const int lane = tid & 63, w = tid >> 6;
    const int m0 = blockIdx.x * 128;

    stage_tile(aggB, m0, As, w, lane);
    stage_tile(wmsgB, 0, Ws, w, lane);
    __syncthreads();

    const int r16 = lane & 15, half = lane >> 4;
    const int wm = (w >> 1) * 64, wn = (w & 1) * 64;
    f32x4 acc[4][4] = {};
#pragma unroll
    for (int kt = 0; kt < 4; ++kt) {
        const int sq = ((kt * 4 + half) ^ r16) << 3;   // short offset in row
        bf16x8 af[4], bfr[4];
#pragma unroll
        for (int t = 0; t < 4; ++t) {
            af[t]  = *(const bf16x8*)&As[(wm + t * 16 + r16) * 128 + sq];
            bfr[t] = *(const bf16x8*)&Ws[(wn + t * 16 + r16) * 128 + sq];
        }
#pragma unroll
        for (int i = 0; i < 4; ++i)
#pragma unroll
            for (int j = 0; j < 4; ++j)
                acc[i][j] = __builtin_amdgcn_mfma_f32_16x16x32_bf16(
                    af[i], bfr[j], acc[i][j], 0, 0, 0);
    }

#pragma unroll
    for (int i = 0; i < 4; ++i)
#pragma unroll
        for (int r = 0; r < 4; ++r) {
            int m = m0 + wm + i * 16 + half * 4 + r;
            if (m < N_NODES) {
#pragma unroll
                for (int j = 0; j < 4; ++j) {
                    int n = wn + j * 16 + r16;
                    float c = acc[i][j][r] + (float)degi[m] * bmsg[n]
                            + colsum[n] * (1.0f / N_NODES);
                    msginB[(size_t)m * 128 + n] = f2bs(c);
                }
            }
        }
}

// merged gi/gh GEMM: y<3 -> gi = msginB@wihB^T + b_ih ; y>=3 -> gh = nodesB@whhB^T + b_hh
__global__ __launch_bounds__(256) void gigh_k(const short* __restrict__ msginB,
                                              const short* __restrict__ nodesB,
                                              const short* __restrict__ wihB,
                                              const short* __restrict__ whhB,
                                              const float* __restrict__ bih,
                                              const float* __restrict__ bhh,
                                              short* __restrict__ gi,
                                              short* __restrict__ gh) {
    __shared__ short As[128 * 128];
    __shared__ short Ws[128 * 128];
    const int tid = threadIdx.x;
    const int lane = tid & 63, w = tid >> 6;
    const int m0 = blockIdx.x * 128;
    const int y = blockIdx.y;
    const short* A; const short* W; const float* bias; short* out; int n0;
    if (y < 3) { A = msginB; W = wihB; bias = bih; out = gi; n0 = y * 128; }
    else       { A = nodesB; W = whhB; bias = bhh; out = gh; n0 = (y - 3) * 128; }

    stage_tile(A, m0, As, w, lane);
    stage_tile(W, n0, Ws, w, lane);
    __syncthreads();

    const int r16 = lane & 15, half = lane >> 4;
    const int wm = (w >> 1) * 64, wn = (w & 1) * 64;
    f32x4 acc[4][4] = {};
#pragma unroll
    for (int kt = 0; kt < 4; ++kt) {
        const int sq = ((kt * 4 + half) ^ r16) << 3;
        bf16x8 af[4], bfr[4];
#pragma unroll
        for (int t = 0; t < 4; ++t) {
            af[t]  = *(const bf16x8*)&As[(wm + t * 16 + r16) * 128 + sq];
            bfr[t] = *(const bf16x8*)&Ws[(wn + t * 16 + r16) * 128 + sq];
        }
#pragma unroll
        for (int i = 0; i < 4; ++i)
#pragma unroll
            for (int j = 0; j < 4; ++j)
                acc[i][j] = __builtin_amdgcn_mfma_f32_16x16x32_bf16(
                    af[i], bfr[j], acc[i][j], 0, 0, 0);
    }

#pragma unroll
    for (int i = 0; i < 4; ++i)
#pragma unroll
        for (int r = 0; r < 4; ++r) {
            int m = m0 + wm + i * 16 + half * 4 + r;
            if (m < N_NODES) {
#pragma unroll
                for (int j = 0; j < 4; ++j) {
                    int n = n0 + wn + j * 16 + r16;
                    out[(size_t)m * 384 + n] = f2bs(acc[i][j][r] + bias[n]);
                }
            }
        }
}

// ---------------------------------------------------------------------------
// K5: GRU gates + LayerNorm + residual. One wave (64 lanes) per node.
// ---------------------------------------------------------------------------
__global__ __launch_bounds__(256) void fuse_k(const float* __restrict__ nodes,
                                              const __hip_bfloat16* __restrict__ gi,
                                              const __hip_bfloat16* __restrict__ gh,
                                              const __hip_bfloat16* __restrict__ msginB,
                                              const float* __restrict__ colsum,
                                              const float* __restrict__ gamma,
                                              const float* __restrict__ beta,
                                              float* __restrict__ out) {
    const int wid = threadIdx.x >> 6;
    const int lane = threadIdx.x & 63;
    const int n = blockIdx.x * 4 + wid;
    if (n >= N_NODES) return;

    const __hip_bfloat16* gir = gi + (size_t)n * 384;
    const __hip_bfloat16* ghr = gh + (size_t)n * 384;

    float hn[2], resid[2];
    float s = 0.f;
#pragma unroll
    for (int t = 0; t < 2; ++t) {
        int c = lane + t * 64;
        float ir = b2f(gir[c]), iz = b2f(gir[128 + c]), inn = b2f(gir[256 + c]);
        float hr = b2f(ghr[c]), hz = b2f(ghr[128 + c]), hhn = b2f(ghr[256 + c]);
        float r = 1.f / (1.f + expf(-(ir + hr)));
        float z = 1.f / (1.f + expf(-(iz + hz)));
        float ng = tanhf(inn + r * hhn);
        float h = nodes[(size_t)n * DIM_H + c];
        hn[t] = (1.f - z) * ng + z * h;
        float mi = b2f(msginB[(size_t)n * DIM_H + c]);
        resid[t] = mi - colsum[c] * (1.0f / N_NODES);   // recover `messages`
        s += hn[t];
    }
#pragma unroll
    for (int o = 32; o; o >>= 1) s += __shfl_xor(s, o, 64);
    float mu = s * (1.0f / DIM_H);
    float v = 0.f;
#pragma unroll
    for (int t = 0; t < 2; ++t) {
        float d = hn[t] - mu;
        v += d * d;
    }
#pragma unroll
    for (int o = 32; o; o >>= 1) v += __shfl_xor(v, o, 64);
    float rstd = rsqrtf(v * (1.0f / DIM_H) + 1e-5f);
#pragma unroll
    for (int t = 0; t < 2; ++t) {
        int c = lane + t * 64;
        float y = gamma[c] * (hn[t] - mu) * rstd + beta[c];
        out[(size_t)n * DIM_H + c] = y + resid[t];
    }
}

// ---------------------------------------------------------------------------
extern "C" void kernel_launch(void* const* d_in, const int* in_sizes, int n_in,
                              void* d_out, int out_size, void* d_ws, size_t ws_size,
                              hipStream_t stream) {
    const float* nodes = (const float*)d_in[0];
    const float* Wmsg  = (const float*)d_in[1];
    const float* bmsg  = (const float*)d_in[2];
    const float* wih   = (const float*)d_in[3];
    const float* whh   = (const float*)d_in[4];
    const float* bih   = (const float*)d_in[5];
    const float* bhh   = (const float*)d_in[6];
    const float* gamma = (const float*)d_in[7];
    const float* beta  = (const float*)d_in[8];
    const int* esrc = (const int*)d_in[9];
    const int* edst = (const int*)d_in[10];
    float* out = (float*)d_out;

    // workspace layout (~105.7 MB); aggB aliases gi (dead before gi is written),
    // bsum aliases head of gh (dead until gigh_k, long after scan2_k)
    char* ws = (char*)d_ws;
    short* gi_s   = (short*)ws;                        // 50000*384*2 = 38.4 MB
    short* aggB   = (short*)ws;                        // NPAD*128*2 = 12.81 MB (alias)
    short* gh_s   = (short*)(ws + 38400000);           // 38.4 MB
    int*   bsum   = (int*)(ws + 38400000);             // 784 B (alias, dead pre-gigh)
    short* nodesB = (short*)(ws + 76800000);           // 12.81 MB (padded)
    short* msginB = (short*)(ws + 89612288);           // 12.81 MB (padded)
    short* wmsgB  = (short*)(ws + 102424576);          // 32 KB
    short* wihB   = (short*)(ws + 102457344);          // 96 KB
    short* whhB   = (short*)(ws + 102555648);          // 96 KB
    float* colsum = (float*)(ws + 102653952);          // 512 B
    int*   cnt    = (int*)(ws + 102654464);            // 200 KB
    int*   rowptr = (int*)(ws + 102854464);            // 200 KB + 4
    int*   pos    = (int*)(ws + 103054472);            // 200 KB
    int*   ssrc   = (int*)(ws + 103254472);            // 2.4 MB -> end ~105.65 MB

    hipMemsetAsync(cnt, 0, N_NODES * sizeof(int), stream);
    hipMemsetAsync(colsum, 0, DIM_H * sizeof(float), stream);
    // zero the 48 padded tail rows of each DMA-read bf16 matrix
    hipMemsetAsync(ws + (size_t)N_NODES * 256, 0, (NPAD - N_NODES) * 256, stream);            // aggB tail
    hipMemsetAsync(ws + 76800000 + (size_t)N_NODES * 256, 0, (NPAD - N_NODES) * 256, stream); // nodesB tail
    hipMemsetAsync(ws + 89612288 + (size_t)N_NODES * 256, 0, (NPAD - N_NODES) * 256, stream); // msginB tail

    colsum_k<<<512, 256, 0, stream>>>(nodes, colsum, nodesB);
    wcvt_k<<<192, 256, 0, stream>>>(Wmsg, wih, whh, wmsgB, wihB, whhB);

    const int EB = (N_EDGES + 255) / 256;
    hist_k<<<EB, 256, 0, stream>>>(edst, cnt);
    bsum_k<<<NB_SCAN, 256, 0, stream>>>(cnt, bsum);
    scan2_k<<<NB_SCAN, 256, 0, stream>>>(cnt, bsum, rowptr, pos);
    reorder_k<<<EB, 256, 0, stream>>>(esrc, edst, pos, ssrc);
    aggregate_k<<<(N_NODES + 3) / 4, 256, 0, stream>>>(nodesB, rowptr, ssrc, aggB);

    const int MB2 = (N_NODES + 127) / 128;  // 391
    mgemm0_k<<<dim3(MB2, 1), 256, 0, stream>>>(aggB, wmsgB, bmsg, cnt, colsum, msginB);
    gigh_k<<<dim3(MB2, 6), 256, 0, stream>>>(msginB, nodesB, wihB, whhB, bih, bhh,
                                             gi_s, gh_s);

    fuse_k<<<(N_NODES + 3) / 4, 256, 0, stream>>>(nodes,
                                                  (const __hip_bfloat16*)gi_s,
                                                  (const __hip_bfloat16*)gh_s,
                                                  (const __hip_bfloat16*)msginB,
                                                  colsum, gamma, beta, out);
}